// Round 8
// baseline (417.908 us; speedup 1.0000x reference)
//
#include <hip/hip_runtime.h>

#define N_NODES 50000
#define N_EDGES 1000000
#define NBLK2   196         // ceil(50000/256)
#define EBLK    3907        // ceil(1e6/256)

// ---- ws layout (bytes) ----
// offset 0 is time-shared: cur[50000] uint during the build (dead after
// k_fill3) -> xr[50000][9][64] float (115.2 MB) -> y2[50000][64] float.
#define A_CUR     0
#define A_XR      0
#define A_Y2      0
#define A_DEGP    115200000  // uint[50000] packed: deg_in<<16 | deg_out
#define A_ROWPTR  115400000  // int[50001]
#define A_BSUM    115600128  // int[196]
#define A_BBASE   115601024  // int[196]
#define A_CSR     115601920  // int2[1e6]: (src*9+etype, src)
#define A_HS      123601920  // float[50000*64]
#define A_WALL    136401920  // float[9*64*64]  (ends 136,549,376)

typedef unsigned int uint32;

// K0: Wall[r][i][o] = sum_b comp[r][b]*basis[b][i][o]; Wall[8] = loop_weight
__global__ void k_wall(const float* __restrict__ comp, const float* __restrict__ basis,
                       const float* __restrict__ loopw, float* __restrict__ Wall) {
    int idx = blockIdx.x * 256 + threadIdx.x;
    if (idx >= 9 * 4096) return;
    int r = idx >> 12, io = idx & 4095;
    float acc;
    if (r < 8) {
        acc = 0.f;
        #pragma unroll
        for (int b = 0; b < 30; ++b) acc += comp[r * 30 + b] * basis[b * 4096 + io];
    } else {
        acc = loopw[io];
    }
    Wall[idx] = acc;
}

// B0: zero the packed degree array (200 KB, L2-resident).
__global__ __launch_bounds__(256) void k_zero(uint32* __restrict__ degp) {
    int v = blockIdx.x * 256 + threadIdx.x;
    if (v < N_NODES) degp[v] = 0;
}

// B1: edge-parallel degree count via global atomics (L2-resident, 2M u32).
// degp[v] = deg_in<<16 | deg_out; fields can't overflow (max deg ~60 << 65536).
__global__ __launch_bounds__(256) void k_count(const int* __restrict__ ei,
                                               uint32* __restrict__ degp) {
    int e = blockIdx.x * 256 + threadIdx.x;
    if (e >= N_EDGES) return;
    atomicAdd(&degp[ei[e]], 1u);                    // src: out-degree
    atomicAdd(&degp[ei[N_EDGES + e]], 0x10000u);    // dst: in-degree
}

// B2: per-256-block sums of deg_in for the two-level scan.
__global__ __launch_bounds__(256) void k_bsum(const uint32* __restrict__ degp,
                                              int* __restrict__ bsum) {
    int t = threadIdx.x, v = blockIdx.x * 256 + t;
    int din = (v < N_NODES) ? (int)(degp[v] >> 16) : 0;
    int r = din;
    #pragma unroll
    for (int d = 1; d < 64; d <<= 1) r += __shfl_xor(r, d);
    __shared__ int wsum[4];
    int lane = t & 63, wid = t >> 6;
    if (lane == 0) wsum[wid] = r;
    __syncthreads();
    if (t == 0) bsum[blockIdx.x] = wsum[0] + wsum[1] + wsum[2] + wsum[3];
}

// B3: exclusive scan of 196 block sums (single block).
__global__ void k_scanb(const int* __restrict__ bsum, int* __restrict__ bbase) {
    int t = threadIdx.x;
    int v = (t < NBLK2) ? bsum[t] : 0;
    int lane = t & 63, wid = t >> 6;
    int x = v;
    #pragma unroll
    for (int d = 1; d < 64; d <<= 1) {
        int y = __shfl_up(x, d);
        if (lane >= d) x += y;
    }
    __shared__ int wsum[4];
    if (lane == 63) wsum[wid] = x;
    __syncthreads();
    int base = 0;
    for (int w = 0; w < wid; ++w) base += wsum[w];
    if (t < NBLK2) bbase[t] = base + x - v;
}

// B4: rowptr[v] via intra-block scan + bbase; seed the fill cursors.
__global__ __launch_bounds__(256) void k_rowptr(const uint32* __restrict__ degp,
                                                const int* __restrict__ bbase,
                                                int* __restrict__ rowptr,
                                                uint32* __restrict__ cur) {
    int t = threadIdx.x, v = blockIdx.x * 256 + t;
    int din = (v < N_NODES) ? (int)(degp[v] >> 16) : 0;
    int lane = t & 63, wid = t >> 6;
    int x = din;
    #pragma unroll
    for (int d = 1; d < 64; d <<= 1) {
        int y = __shfl_up(x, d);
        if (lane >= d) x += y;
    }
    __shared__ int wsum[4];
    if (lane == 63) wsum[wid] = x;
    __syncthreads();
    int base = bbase[blockIdx.x];
    for (int w = 0; w < wid; ++w) base += wsum[w];
    int start = base + x - din;
    if (v < N_NODES) {
        rowptr[v] = start;
        cur[v] = (uint32)start;
        if (v == N_NODES - 1) rowptr[N_NODES] = start + din;
    }
}

// B5: edge-parallel CSR fill via cursor atomics (1M u32 atomics, L2-resident).
// Intra-row order is nondeterministic — fine, aggregation is a sum.
__global__ __launch_bounds__(256) void k_fill3(const int* __restrict__ ei,
                                               const int* __restrict__ etype,
                                               uint32* __restrict__ cur,
                                               int2* __restrict__ csr) {
    int e = blockIdx.x * 256 + threadIdx.x;
    if (e >= N_EDGES) return;
    int s = ei[e], d = ei[N_EDGES + e], ty = etype[e];
    uint32 pos = atomicAdd(&cur[d], 1u);
    csr[pos] = make_int2(s * 9 + ty, s);
}

// K6 (= proven v3, 69 us): xr[n][r][64] = x[n][:] @ Wall[r].
// 256 nodes x 64 outs per block, 256 threads, 8x8 per-thread tile, K split
// into two 32-wide phases: LDS = At[32][256] 32 KB + Wt[32][64] 8 KB = 40 KB.
// DO NOT touch occupancy: 4-phase split inflated VGPR to 136 (107 us, v5);
// launch_bounds(256,6) forced 40 VGPR and spilled acc to scratch (785 us, v6).
__global__ __launch_bounds__(256) void k_xr(const float* __restrict__ x,
                                            const float* __restrict__ Wall,
                                            float* __restrict__ xr) {
    __shared__ __align__(16) float At[32 * 256];   // 32 KB
    __shared__ __align__(16) float Wt[32 * 64];    // 8 KB
    int t = threadIdx.x;
    int n0 = blockIdx.x * 256;
    int r = blockIdx.y;
    int og = t & 7, ng = t >> 3;        // o = og*8 .. +7, nodes = n0 + ng*8 .. +7
    float acc[8][8];
    #pragma unroll
    for (int i = 0; i < 8; ++i)
        #pragma unroll
        for (int j = 0; j < 8; ++j) acc[i][j] = 0.f;

    #pragma unroll
    for (int ph = 0; ph < 2; ++ph) {
        if (ph) __syncthreads();   // all waves done reading phase-0 tiles
        // stage A transposed+swizzled: 256 nodes x 32 k
        #pragma unroll
        for (int j = 0; j < 8; ++j) {
            int f4 = t + j * 256;          // float4 index, < 2048
            int n = f4 >> 3, k4 = f4 & 7;  // 8 float4 per 32-k node row
            float4 v = make_float4(0.f, 0.f, 0.f, 0.f);
            if (n0 + n < N_NODES)
                v = *(const float4*)&x[(n0 + n) * 64 + ph * 32 + k4 * 4];
            int sl = n >> 2, nl = n & 3, kb = k4 * 4;
            At[(kb + 0) * 256 + (((sl ^ ((kb + 0) & 7)) << 2) | nl)] = v.x;
            At[(kb + 1) * 256 + (((sl ^ ((kb + 1) & 7)) << 2) | nl)] = v.y;
            At[(kb + 2) * 256 + (((sl ^ ((kb + 2) & 7)) << 2) | nl)] = v.z;
            At[(kb + 3) * 256 + (((sl ^ ((kb + 3) & 7)) << 2) | nl)] = v.w;
        }
        // stage W (linear copy, conflict-free)
        #pragma unroll
        for (int j = 0; j < 8; ++j) {
            int f = t + j * 256;
            Wt[f] = Wall[r * 4096 + ph * 2048 + f];
        }
        __syncthreads();
        #pragma unroll 4
        for (int k = 0; k < 32; ++k) {
            int c = k & 7;
            float4 aA = *(const float4*)&At[k * 256 + (((2 * ng) ^ c) << 2)];
            float4 aB = *(const float4*)&At[k * 256 + (((2 * ng + 1) ^ c) << 2)];
            float4 w0 = *(const float4*)&Wt[k * 64 + og * 8];
            float4 w1 = *(const float4*)&Wt[k * 64 + og * 8 + 4];
            float a_[8] = {aA.x, aA.y, aA.z, aA.w, aB.x, aB.y, aB.z, aB.w};
            float w_[8] = {w0.x, w0.y, w0.z, w0.w, w1.x, w1.y, w1.z, w1.w};
            #pragma unroll
            for (int i = 0; i < 8; ++i)
                #pragma unroll
                for (int j = 0; j < 8; ++j) acc[i][j] += a_[i] * w_[j];
        }
    }
    #pragma unroll
    for (int i = 0; i < 8; ++i) {
        int n = n0 + ng * 8 + i;
        if (n < N_NODES) {
            *(float4*)&xr[n * 576 + r * 64 + og * 8] =
                make_float4(acc[i][0], acc[i][1], acc[i][2], acc[i][3]);
            *(float4*)&xr[n * 576 + r * 64 + og * 8 + 4] =
                make_float4(acc[i][4], acc[i][5], acc[i][6], acc[i][7]);
        }
    }
}

// K7: hs[v] = (sum_in xr[csr.x] + xr[v*9+8] + bias1) * rsqrt(deg_out[v])
__global__ __launch_bounds__(256) void k_agg1(const float* __restrict__ xr,
                                              const int2* __restrict__ csr,
                                              const int* __restrict__ rowptr,
                                              const uint32* __restrict__ degp,
                                              const float* __restrict__ bias1,
                                              float* __restrict__ hs) {
    int wid = threadIdx.x >> 6, lane = threadIdx.x & 63;
    int v = blockIdx.x * 4 + wid;
    if (v >= N_NODES) return;
    float acc = xr[(v * 9 + 8) * 64 + lane] + bias1[lane];
    int j = rowptr[v], end = rowptr[v + 1];
    for (; j + 4 <= end; j += 4) {
        int r0 = csr[j].x, r1 = csr[j + 1].x, r2 = csr[j + 2].x, r3 = csr[j + 3].x;
        float a0 = xr[r0 * 64 + lane], a1 = xr[r1 * 64 + lane];
        float a2 = xr[r2 * 64 + lane], a3 = xr[r3 * 64 + lane];
        acc += a0; acc += a1; acc += a2; acc += a3;
    }
    for (; j < end; ++j) acc += xr[csr[j].x * 64 + lane];
    float dg = (float)(degp[v] & 0xffffu);
    if (dg < 1.f) dg = 1.f;
    hs[v * 64 + lane] = acc * rsqrtf(dg);
}

// K8a: y2[v] = rsqrt(deg_in[v]) * sum_in hs[csr.y] — gather only.
// y2 lives at ws offset 0 (xr is dead after k_agg1).
__global__ __launch_bounds__(256) void k_agg2(const float* __restrict__ hs,
                                              const int2* __restrict__ csr,
                                              const int* __restrict__ rowptr,
                                              const uint32* __restrict__ degp,
                                              float* __restrict__ y2) {
    int wid = threadIdx.x >> 6, lane = threadIdx.x & 63;
    int v = blockIdx.x * 4 + wid;
    if (v >= N_NODES) return;
    float acc = 0.f;
    int j = rowptr[v], end = rowptr[v + 1];
    for (; j + 4 <= end; j += 4) {
        int r0 = csr[j].y, r1 = csr[j + 1].y, r2 = csr[j + 2].y, r3 = csr[j + 3].y;
        float a0 = hs[r0 * 64 + lane], a1 = hs[r1 * 64 + lane];
        float a2 = hs[r2 * 64 + lane], a3 = hs[r3 * 64 + lane];
        acc += a0; acc += a1; acc += a2; acc += a3;
    }
    for (; j < end; ++j) acc += hs[csr[j].y * 64 + lane];
    float dg = (float)(degp[v] >> 16);
    if (dg < 1.f) dg = 1.f;
    y2[v * 64 + lane] = acc * rsqrtf(dg);
}

// K8b: out = y2 @ w2 + bias2 — batched tiled GEMM (v3-k_xr structure).
__global__ __launch_bounds__(256) void k_gemm2(const float* __restrict__ y2,
                                               const float* __restrict__ w2,
                                               const float* __restrict__ bias2,
                                               float* __restrict__ out) {
    __shared__ __align__(16) float At[32 * 256];   // 32 KB
    __shared__ __align__(16) float Wt[32 * 64];    // 8 KB
    int t = threadIdx.x;
    int n0 = blockIdx.x * 256;
    int og = t & 7, ng = t >> 3;
    float acc[8][8];
    #pragma unroll
    for (int i = 0; i < 8; ++i)
        #pragma unroll
        for (int j = 0; j < 8; ++j) acc[i][j] = 0.f;

    #pragma unroll
    for (int ph = 0; ph < 2; ++ph) {
        if (ph) __syncthreads();
        #pragma unroll
        for (int j = 0; j < 8; ++j) {
            int f4 = t + j * 256;
            int n = f4 >> 3, k4 = f4 & 7;
            float4 v = make_float4(0.f, 0.f, 0.f, 0.f);
            if (n0 + n < N_NODES)
                v = *(const float4*)&y2[(n0 + n) * 64 + ph * 32 + k4 * 4];
            int sl = n >> 2, nl = n & 3, kb = k4 * 4;
            At[(kb + 0) * 256 + (((sl ^ ((kb + 0) & 7)) << 2) | nl)] = v.x;
            At[(kb + 1) * 256 + (((sl ^ ((kb + 1) & 7)) << 2) | nl)] = v.y;
            At[(kb + 2) * 256 + (((sl ^ ((kb + 2) & 7)) << 2) | nl)] = v.z;
            At[(kb + 3) * 256 + (((sl ^ ((kb + 3) & 7)) << 2) | nl)] = v.w;
        }
        #pragma unroll
        for (int j = 0; j < 8; ++j) {
            int f = t + j * 256;
            Wt[f] = w2[ph * 2048 + f];
        }
        __syncthreads();
        #pragma unroll 4
        for (int k = 0; k < 32; ++k) {
            int c = k & 7;
            float4 aA = *(const float4*)&At[k * 256 + (((2 * ng) ^ c) << 2)];
            float4 aB = *(const float4*)&At[k * 256 + (((2 * ng + 1) ^ c) << 2)];
            float4 w0 = *(const float4*)&Wt[k * 64 + og * 8];
            float4 w1 = *(const float4*)&Wt[k * 64 + og * 8 + 4];
            float a_[8] = {aA.x, aA.y, aA.z, aA.w, aB.x, aB.y, aB.z, aB.w};
            float w_[8] = {w0.x, w0.y, w0.z, w0.w, w1.x, w1.y, w1.z, w1.w};
            #pragma unroll
            for (int i = 0; i < 8; ++i)
                #pragma unroll
                for (int j = 0; j < 8; ++j) acc[i][j] += a_[i] * w_[j];
        }
    }
    float4 b0 = *(const float4*)&bias2[og * 8];
    float4 b1 = *(const float4*)&bias2[og * 8 + 4];
    #pragma unroll
    for (int i = 0; i < 8; ++i) {
        int n = n0 + ng * 8 + i;
        if (n < N_NODES) {
            *(float4*)&out[n * 64 + og * 8] =
                make_float4(acc[i][0] + b0.x, acc[i][1] + b0.y,
                            acc[i][2] + b0.z, acc[i][3] + b0.w);
            *(float4*)&out[n * 64 + og * 8 + 4] =
                make_float4(acc[i][4] + b1.x, acc[i][5] + b1.y,
                            acc[i][6] + b1.z, acc[i][7] + b1.w);
        }
    }
}

extern "C" void kernel_launch(void* const* d_in, const int* in_sizes, int n_in,
                              void* d_out, int out_size, void* d_ws, size_t ws_size,
                              hipStream_t stream) {
    const float* x      = (const float*)d_in[0];
    const int*   ei     = (const int*)d_in[1];   // [2E]: src then dst
    const int*   etype  = (const int*)d_in[3];
    const float* basis  = (const float*)d_in[4];
    const float* comp   = (const float*)d_in[5];
    const float* loopw  = (const float*)d_in[6];
    const float* bias1  = (const float*)d_in[7];
    const float* w2     = (const float*)d_in[8];
    const float* bias2  = (const float*)d_in[9];
    float* out = (float*)d_out;

    char* ws = (char*)d_ws;
    uint32* cur    = (uint32*)(ws + A_CUR);    // build-time only; dies at k_xr
    float*  xr     = (float*)(ws + A_XR);      // aliases cur region
    float*  y2     = (float*)(ws + A_Y2);      // aliases xr; written after agg1
    uint32* degp   = (uint32*)(ws + A_DEGP);
    int*    rowptr = (int*)(ws + A_ROWPTR);
    int*    bsum   = (int*)(ws + A_BSUM);
    int*    bbase  = (int*)(ws + A_BBASE);
    int2*   csr    = (int2*)(ws + A_CSR);
    float*  hs     = (float*)(ws + A_HS);
    float*  Wall   = (float*)(ws + A_WALL);

    k_wall<<<144, 256, 0, stream>>>(comp, basis, loopw, Wall);
    k_zero<<<NBLK2, 256, 0, stream>>>(degp);
    k_count<<<EBLK, 256, 0, stream>>>(ei, degp);
    k_bsum<<<NBLK2, 256, 0, stream>>>(degp, bsum);
    k_scanb<<<1, 256, 0, stream>>>(bsum, bbase);
    k_rowptr<<<NBLK2, 256, 0, stream>>>(degp, bbase, rowptr, cur);
    k_fill3<<<EBLK, 256, 0, stream>>>(ei, etype, cur, csr);
    k_xr<<<dim3((N_NODES + 255) / 256, 9), 256, 0, stream>>>(x, Wall, xr);
    k_agg1<<<N_NODES / 4, 256, 0, stream>>>(xr, csr, rowptr, degp, bias1, hs);
    k_agg2<<<N_NODES / 4, 256, 0, stream>>>(hs, csr, rowptr, degp, y2);
    k_gemm2<<<(N_NODES + 255) / 256, 256, 0, stream>>>(y2, w2, bias2, out);
}

// Round 9
// 330.096 us; speedup vs baseline: 1.2660x; 1.2660x over previous
//
#include <hip/hip_runtime.h>

#define N_NODES 50000
#define N_EDGES 1000000
#define NB      64          // edge chunks
#define CHUNK   15625       // 64*15625 = 1,000,000 = E
#define NQ      4           // node ranges per chunk (blockIdx.y)
#define QN      12512       // words per range (16B-aligned); 4*12512 = 50048 >= N
#define NBLK2   196         // ceil(50000/256)

// ---- ws layout (bytes) ----
// part[NB][50000] uint (12.8 MB) lives at 0 and is DEAD after k_fill2;
// xr[50000][9][64] float (115.2 MB) reuses offset 0 after the build;
// y2[50000][64] float (12.8 MB) reuses offset 0 after k_agg1 consumes xr.
#define A_PART    0
#define A_XR      0
#define A_Y2      0
#define A_DEGP    115200000  // uint[50000] packed: deg_in<<16 | deg_out
#define A_ROWPTR  115400000  // int[50001]
#define A_BSUM    115600128  // int[196]
#define A_BBASE   115601024  // int[196]
#define A_CSR     115601920  // int2[1e6]: (src*9+etype, src)
#define A_HS      123601920  // float[50000*64]
#define A_WALL    136401920  // float[9*64*64]  (ends 136,549,376)

typedef unsigned int uint32;

// K0: Wall[r][i][o] = sum_b comp[r][b]*basis[b][i][o]; Wall[8] = loop_weight
__global__ void k_wall(const float* __restrict__ comp, const float* __restrict__ basis,
                       const float* __restrict__ loopw, float* __restrict__ Wall) {
    int idx = blockIdx.x * 256 + threadIdx.x;
    if (idx >= 9 * 4096) return;
    int r = idx >> 12, io = idx & 4095;
    float acc;
    if (r < 8) {
        acc = 0.f;
        #pragma unroll
        for (int b = 0; b < 30; ++b) acc += comp[r * 30 + b] * basis[b * 4096 + io];
    } else {
        acc = loopw[io];
    }
    Wall[idx] = acc;
}

// K1: per-(chunk, node-range) packed histogram via LDS atomics.
// part[b][v] = (in_count<<16) | out_count for chunk b.
// NQ=4 x 50 KB LDS (vs 8 x 25 KB): halves the edge-list passes.
// NOTE (v8 lesson): global-atomic degree count was 10x slower (87 us for 2M
// random atomics, ~23 Gop/s) — keep the LDS-privatized multi-pass build.
__global__ __launch_bounds__(256) void k_hist2(const int* __restrict__ ei,
                                               uint32* __restrict__ part) {
    __shared__ __align__(16) uint32 h[QN];
    int t = threadIdx.x, b = blockIdx.x, q = blockIdx.y;
    int lo = q * QN;
    int nq = N_NODES - lo; if (nq > QN) nq = QN;
    int4* h4 = (int4*)h;
    for (int i = t; i < QN / 4; i += 256) h4[i] = make_int4(0, 0, 0, 0);
    __syncthreads();
    int e0 = b * CHUNK, e1 = e0 + CHUNK;
    if (e1 > N_EDGES) e1 = N_EDGES;
    for (int e = e0 + t; e < e1; e += 256) {
        int s = ei[e], d = ei[N_EDGES + e];
        unsigned rs = (unsigned)(s - lo), rd = (unsigned)(d - lo);
        if (rs < (unsigned)QN) atomicAdd(&h[rs], 1u);
        if (rd < (unsigned)QN) atomicAdd(&h[rd], 0x10000u);
    }
    __syncthreads();
    int4* d4 = (int4*)(part + b * N_NODES + lo);
    const int4* s4 = (const int4*)h;
    for (int i = t; i < nq / 4; i += 256) d4[i] = s4[i];
}

// K2: degp[v] = sum_b part[b][v]; block sums of deg_in for the scan.
__global__ __launch_bounds__(256) void k_merge(const uint32* __restrict__ part,
                                               uint32* __restrict__ degp,
                                               int* __restrict__ bsum) {
    int t = threadIdx.x, v = blockIdx.x * 256 + t;
    uint32 s = 0;
    if (v < N_NODES) {
        #pragma unroll 8
        for (int b = 0; b < NB; ++b) s += part[b * N_NODES + v];
        degp[v] = s;
    }
    int din = (int)(s >> 16);
    int r = din;
    #pragma unroll
    for (int d = 1; d < 64; d <<= 1) r += __shfl_xor(r, d);
    __shared__ int wsum[4];
    int lane = t & 63, wid = t >> 6;
    if (lane == 0) wsum[wid] = r;
    __syncthreads();
    if (t == 0) bsum[blockIdx.x] = wsum[0] + wsum[1] + wsum[2] + wsum[3];
}

// K3: exclusive scan of 196 block sums (single block).
__global__ void k_scanb(const int* __restrict__ bsum, int* __restrict__ bbase) {
    int t = threadIdx.x;
    int v = (t < NBLK2) ? bsum[t] : 0;
    int lane = t & 63, wid = t >> 6;
    int x = v;
    #pragma unroll
    for (int d = 1; d < 64; d <<= 1) {
        int y = __shfl_up(x, d);
        if (lane >= d) x += y;
    }
    __shared__ int wsum[4];
    if (lane == 63) wsum[wid] = x;
    __syncthreads();
    int base = 0;
    for (int w = 0; w < wid; ++w) base += wsum[w];
    if (t < NBLK2) bbase[t] = base + x - v;
}

// K4: rowptr[v]; convert part[b][v] in-place into fill offsets.
__global__ __launch_bounds__(256) void k_base(uint32* __restrict__ part,
                                              const uint32* __restrict__ degp,
                                              const int* __restrict__ bbase,
                                              int* __restrict__ rowptr) {
    int t = threadIdx.x, v = blockIdx.x * 256 + t;
    int din = (v < N_NODES) ? (int)(degp[v] >> 16) : 0;
    int lane = t & 63, wid = t >> 6;
    int x = din;
    #pragma unroll
    for (int d = 1; d < 64; d <<= 1) {
        int y = __shfl_up(x, d);
        if (lane >= d) x += y;
    }
    __shared__ int wsum[4];
    if (lane == 63) wsum[wid] = x;
    __syncthreads();
    int base = bbase[blockIdx.x];
    for (int w = 0; w < wid; ++w) base += wsum[w];
    int start = base + x - din;
    if (v < N_NODES) {
        rowptr[v] = start;
        if (v == N_NODES - 1) rowptr[N_NODES] = start + din;
        uint32 run = (uint32)start;
        for (int b = 0; b < NB; ++b) {
            uint32 p = part[b * N_NODES + v];
            part[b * N_NODES + v] = run;
            run += (p >> 16);
        }
    }
}

// K5: scatter edges into CSR slots; LDS cursors seeded from fillbase.
__global__ __launch_bounds__(256) void k_fill2(const int* __restrict__ ei,
                                               const int* __restrict__ etype,
                                               const uint32* __restrict__ fillbase,
                                               int2* __restrict__ csr) {
    __shared__ __align__(16) uint32 cur[QN];
    int t = threadIdx.x, b = blockIdx.x, q = blockIdx.y;
    int lo = q * QN;
    int nq = N_NODES - lo; if (nq > QN) nq = QN;
    const int4* s4 = (const int4*)(fillbase + b * N_NODES + lo);
    int4* c4 = (int4*)cur;
    for (int i = t; i < nq / 4; i += 256) c4[i] = s4[i];
    __syncthreads();
    int e0 = b * CHUNK, e1 = e0 + CHUNK;
    if (e1 > N_EDGES) e1 = N_EDGES;
    for (int e = e0 + t; e < e1; e += 256) {
        int d = ei[N_EDGES + e];
        unsigned rd = (unsigned)(d - lo);
        if (rd < (unsigned)QN) {
            int s = ei[e], ty = etype[e];
            uint32 pos = atomicAdd(&cur[rd], 1u);
            csr[pos] = make_int2(s * 9 + ty, s);
        }
    }
}

// K6 (= proven v3, 69 us): xr[n][r][64] = x[n][:] @ Wall[r].
// 256 nodes x 64 outs per block, 256 threads, 8x8 per-thread tile, K split
// into two 32-wide phases: LDS = At[32][256] 32 KB + Wt[32][64] 8 KB = 40 KB.
// DO NOT touch occupancy: 4-phase split inflated VGPR to 136 (107 us, v5);
// launch_bounds(256,6) forced 40 VGPR and spilled acc to scratch (785 us, v6).
__global__ __launch_bounds__(256) void k_xr(const float* __restrict__ x,
                                            const float* __restrict__ Wall,
                                            float* __restrict__ xr) {
    __shared__ __align__(16) float At[32 * 256];   // 32 KB
    __shared__ __align__(16) float Wt[32 * 64];    // 8 KB
    int t = threadIdx.x;
    int n0 = blockIdx.x * 256;
    int r = blockIdx.y;
    int og = t & 7, ng = t >> 3;        // o = og*8 .. +7, nodes = n0 + ng*8 .. +7
    float acc[8][8];
    #pragma unroll
    for (int i = 0; i < 8; ++i)
        #pragma unroll
        for (int j = 0; j < 8; ++j) acc[i][j] = 0.f;

    #pragma unroll
    for (int ph = 0; ph < 2; ++ph) {
        if (ph) __syncthreads();   // all waves done reading phase-0 tiles
        // stage A transposed+swizzled: 256 nodes x 32 k
        #pragma unroll
        for (int j = 0; j < 8; ++j) {
            int f4 = t + j * 256;          // float4 index, < 2048
            int n = f4 >> 3, k4 = f4 & 7;  // 8 float4 per 32-k node row
            float4 v = make_float4(0.f, 0.f, 0.f, 0.f);
            if (n0 + n < N_NODES)
                v = *(const float4*)&x[(n0 + n) * 64 + ph * 32 + k4 * 4];
            int sl = n >> 2, nl = n & 3, kb = k4 * 4;
            At[(kb + 0) * 256 + (((sl ^ ((kb + 0) & 7)) << 2) | nl)] = v.x;
            At[(kb + 1) * 256 + (((sl ^ ((kb + 1) & 7)) << 2) | nl)] = v.y;
            At[(kb + 2) * 256 + (((sl ^ ((kb + 2) & 7)) << 2) | nl)] = v.z;
            At[(kb + 3) * 256 + (((sl ^ ((kb + 3) & 7)) << 2) | nl)] = v.w;
        }
        // stage W (linear copy, conflict-free)
        #pragma unroll
        for (int j = 0; j < 8; ++j) {
            int f = t + j * 256;
            Wt[f] = Wall[r * 4096 + ph * 2048 + f];
        }
        __syncthreads();
        #pragma unroll 4
        for (int k = 0; k < 32; ++k) {
            int c = k & 7;
            float4 aA = *(const float4*)&At[k * 256 + (((2 * ng) ^ c) << 2)];
            float4 aB = *(const float4*)&At[k * 256 + (((2 * ng + 1) ^ c) << 2)];
            float4 w0 = *(const float4*)&Wt[k * 64 + og * 8];
            float4 w1 = *(const float4*)&Wt[k * 64 + og * 8 + 4];
            float a_[8] = {aA.x, aA.y, aA.z, aA.w, aB.x, aB.y, aB.z, aB.w};
            float w_[8] = {w0.x, w0.y, w0.z, w0.w, w1.x, w1.y, w1.z, w1.w};
            #pragma unroll
            for (int i = 0; i < 8; ++i)
                #pragma unroll
                for (int j = 0; j < 8; ++j) acc[i][j] += a_[i] * w_[j];
        }
    }
    #pragma unroll
    for (int i = 0; i < 8; ++i) {
        int n = n0 + ng * 8 + i;
        if (n < N_NODES) {
            *(float4*)&xr[n * 576 + r * 64 + og * 8] =
                make_float4(acc[i][0], acc[i][1], acc[i][2], acc[i][3]);
            *(float4*)&xr[n * 576 + r * 64 + og * 8 + 4] =
                make_float4(acc[i][4], acc[i][5], acc[i][6], acc[i][7]);
        }
    }
}

// K7: hs[v] = (sum_in xr[csr.x] + xr[v*9+8] + bias1) * rsqrt(deg_out[v])
__global__ __launch_bounds__(256) void k_agg1(const float* __restrict__ xr,
                                              const int2* __restrict__ csr,
                                              const int* __restrict__ rowptr,
                                              const uint32* __restrict__ degp,
                                              const float* __restrict__ bias1,
                                              float* __restrict__ hs) {
    int wid = threadIdx.x >> 6, lane = threadIdx.x & 63;
    int v = blockIdx.x * 4 + wid;
    if (v >= N_NODES) return;
    float acc = xr[(v * 9 + 8) * 64 + lane] + bias1[lane];
    int j = rowptr[v], end = rowptr[v + 1];
    for (; j + 4 <= end; j += 4) {
        int r0 = csr[j].x, r1 = csr[j + 1].x, r2 = csr[j + 2].x, r3 = csr[j + 3].x;
        float a0 = xr[r0 * 64 + lane], a1 = xr[r1 * 64 + lane];
        float a2 = xr[r2 * 64 + lane], a3 = xr[r3 * 64 + lane];
        acc += a0; acc += a1; acc += a2; acc += a3;
    }
    for (; j < end; ++j) acc += xr[csr[j].x * 64 + lane];
    float dg = (float)(degp[v] & 0xffffu);
    if (dg < 1.f) dg = 1.f;
    hs[v * 64 + lane] = acc * rsqrtf(dg);
}

// K8a: y2[v] = rsqrt(deg_in[v]) * sum_in hs[csr.y] — gather only.
// y2 lives at ws offset 0 (xr is dead after k_agg1).
__global__ __launch_bounds__(256) void k_agg2(const float* __restrict__ hs,
                                              const int2* __restrict__ csr,
                                              const int* __restrict__ rowptr,
                                              const uint32* __restrict__ degp,
                                              float* __restrict__ y2) {
    int wid = threadIdx.x >> 6, lane = threadIdx.x & 63;
    int v = blockIdx.x * 4 + wid;
    if (v >= N_NODES) return;
    float acc = 0.f;
    int j = rowptr[v], end = rowptr[v + 1];
    for (; j + 4 <= end; j += 4) {
        int r0 = csr[j].y, r1 = csr[j + 1].y, r2 = csr[j + 2].y, r3 = csr[j + 3].y;
        float a0 = hs[r0 * 64 + lane], a1 = hs[r1 * 64 + lane];
        float a2 = hs[r2 * 64 + lane], a3 = hs[r3 * 64 + lane];
        acc += a0; acc += a1; acc += a2; acc += a3;
    }
    for (; j < end; ++j) acc += hs[csr[j].y * 64 + lane];
    float dg = (float)(degp[v] >> 16);
    if (dg < 1.f) dg = 1.f;
    y2[v * 64 + lane] = acc * rsqrtf(dg);
}

// K8b: out = y2 @ w2 + bias2 — batched tiled GEMM (v3-k_xr structure).
__global__ __launch_bounds__(256) void k_gemm2(const float* __restrict__ y2,
                                               const float* __restrict__ w2,
                                               const float* __restrict__ bias2,
                                               float* __restrict__ out) {
    __shared__ __align__(16) float At[32 * 256];   // 32 KB
    __shared__ __align__(16) float Wt[32 * 64];    // 8 KB
    int t = threadIdx.x;
    int n0 = blockIdx.x * 256;
    int og = t & 7, ng = t >> 3;
    float acc[8][8];
    #pragma unroll
    for (int i = 0; i < 8; ++i)
        #pragma unroll
        for (int j = 0; j < 8; ++j) acc[i][j] = 0.f;

    #pragma unroll
    for (int ph = 0; ph < 2; ++ph) {
        if (ph) __syncthreads();
        #pragma unroll
        for (int j = 0; j < 8; ++j) {
            int f4 = t + j * 256;
            int n = f4 >> 3, k4 = f4 & 7;
            float4 v = make_float4(0.f, 0.f, 0.f, 0.f);
            if (n0 + n < N_NODES)
                v = *(const float4*)&y2[(n0 + n) * 64 + ph * 32 + k4 * 4];
            int sl = n >> 2, nl = n & 3, kb = k4 * 4;
            At[(kb + 0) * 256 + (((sl ^ ((kb + 0) & 7)) << 2) | nl)] = v.x;
            At[(kb + 1) * 256 + (((sl ^ ((kb + 1) & 7)) << 2) | nl)] = v.y;
            At[(kb + 2) * 256 + (((sl ^ ((kb + 2) & 7)) << 2) | nl)] = v.z;
            At[(kb + 3) * 256 + (((sl ^ ((kb + 3) & 7)) << 2) | nl)] = v.w;
        }
        #pragma unroll
        for (int j = 0; j < 8; ++j) {
            int f = t + j * 256;
            Wt[f] = w2[ph * 2048 + f];
        }
        __syncthreads();
        #pragma unroll 4
        for (int k = 0; k < 32; ++k) {
            int c = k & 7;
            float4 aA = *(const float4*)&At[k * 256 + (((2 * ng) ^ c) << 2)];
            float4 aB = *(const float4*)&At[k * 256 + (((2 * ng + 1) ^ c) << 2)];
            float4 w0 = *(const float4*)&Wt[k * 64 + og * 8];
            float4 w1 = *(const float4*)&Wt[k * 64 + og * 8 + 4];
            float a_[8] = {aA.x, aA.y, aA.z, aA.w, aB.x, aB.y, aB.z, aB.w};
            float w_[8] = {w0.x, w0.y, w0.z, w0.w, w1.x, w1.y, w1.z, w1.w};
            #pragma unroll
            for (int i = 0; i < 8; ++i)
                #pragma unroll
                for (int j = 0; j < 8; ++j) acc[i][j] += a_[i] * w_[j];
        }
    }
    float4 b0 = *(const float4*)&bias2[og * 8];
    float4 b1 = *(const float4*)&bias2[og * 8 + 4];
    #pragma unroll
    for (int i = 0; i < 8; ++i) {
        int n = n0 + ng * 8 + i;
        if (n < N_NODES) {
            *(float4*)&out[n * 64 + og * 8] =
                make_float4(acc[i][0] + b0.x, acc[i][1] + b0.y,
                            acc[i][2] + b0.z, acc[i][3] + b0.w);
            *(float4*)&out[n * 64 + og * 8 + 4] =
                make_float4(acc[i][4] + b1.x, acc[i][5] + b1.y,
                            acc[i][6] + b1.z, acc[i][7] + b1.w);
        }
    }
}

extern "C" void kernel_launch(void* const* d_in, const int* in_sizes, int n_in,
                              void* d_out, int out_size, void* d_ws, size_t ws_size,
                              hipStream_t stream) {
    const float* x      = (const float*)d_in[0];
    const int*   ei     = (const int*)d_in[1];   // [2E]: src then dst
    const int*   etype  = (const int*)d_in[3];
    const float* basis  = (const float*)d_in[4];
    const float* comp   = (const float*)d_in[5];
    const float* loopw  = (const float*)d_in[6];
    const float* bias1  = (const float*)d_in[7];
    const float* w2     = (const float*)d_in[8];
    const float* bias2  = (const float*)d_in[9];
    float* out = (float*)d_out;

    char* ws = (char*)d_ws;
    uint32* part   = (uint32*)(ws + A_PART);
    float*  xr     = (float*)(ws + A_XR);      // aliases part; written after fill
    float*  y2     = (float*)(ws + A_Y2);      // aliases xr; written after agg1
    uint32* degp   = (uint32*)(ws + A_DEGP);
    int*    rowptr = (int*)(ws + A_ROWPTR);
    int*    bsum   = (int*)(ws + A_BSUM);
    int*    bbase  = (int*)(ws + A_BBASE);
    int2*   csr    = (int2*)(ws + A_CSR);
    float*  hs     = (float*)(ws + A_HS);
    float*  Wall   = (float*)(ws + A_WALL);

    k_wall<<<144, 256, 0, stream>>>(comp, basis, loopw, Wall);
    k_hist2<<<dim3(NB, NQ), 256, 0, stream>>>(ei, part);
    k_merge<<<NBLK2, 256, 0, stream>>>(part, degp, bsum);
    k_scanb<<<1, 256, 0, stream>>>(bsum, bbase);
    k_base<<<NBLK2, 256, 0, stream>>>(part, degp, bbase, rowptr);
    k_fill2<<<dim3(NB, NQ), 256, 0, stream>>>(ei, etype, part, csr);
    k_xr<<<dim3((N_NODES + 255) / 256, 9), 256, 0, stream>>>(x, Wall, xr);
    k_agg1<<<N_NODES / 4, 256, 0, stream>>>(xr, csr, rowptr, degp, bias1, hs);
    k_agg2<<<N_NODES / 4, 256, 0, stream>>>(hs, csr, rowptr, degp, y2);
    k_gemm2<<<(N_NODES + 255) / 256, 256, 0, stream>>>(y2, w2, bias2, out);
}

// Round 10
// 294.596 us; speedup vs baseline: 1.4186x; 1.1205x over previous
//
#include <hip/hip_runtime.h>

#define N_NODES 50000
#define N_EDGES 1000000
#define NB      128         // edge chunks
#define CHUNK   7813        // 128*7813 = 1,000,064 >= E
#define NQ      8           // node ranges per chunk (blockIdx.y)
#define QN      6256        // words per range (16B-aligned); 8*6256 = 50048 >= N
#define NBLK2   196         // ceil(50000/256)

// ---- ws layout (bytes) ----
// Offset 0 is time-shared: part[NB][50000] u32 (25.6 MB, dead after k_fill2)
// -> xr16[50000][9][64] bf16 (57.6 MB, dead after k_agg1)
// -> y2[50000][64] f32 (12.8 MB).
// hs16[50000][64] bf16 (6.4 MB) lives in the old hs slot.
#define A_PART    0
#define A_XR      0
#define A_Y2      0
#define A_DEGP    115200000  // uint[50000] packed: deg_in<<16 | deg_out
#define A_ROWPTR  115400000  // int[50001]
#define A_BSUM    115600128  // int[196]
#define A_BBASE   115601024  // int[196]
#define A_CSR     115601920  // int2[1e6]: (src*9+etype, src)
#define A_HS      123601920  // bf16[50000*64]
#define A_WALL    136401920  // float[9*64*64]  (ends 136,549,376)

typedef unsigned int uint32;
typedef unsigned short ushort16;

// bf16 storage helpers: RNE pack, shift unpack. All math stays fp32.
__device__ inline ushort16 f2bf(float f) {
    uint32 u = __float_as_uint(f);
    return (ushort16)((u + 0x7FFFu + ((u >> 16) & 1u)) >> 16);
}
__device__ inline float bf2f(ushort16 h) {
    return __uint_as_float(((uint32)h) << 16);
}

// K0: Wall[r][i][o] = sum_b comp[r][b]*basis[b][i][o]; Wall[8] = loop_weight
__global__ void k_wall(const float* __restrict__ comp, const float* __restrict__ basis,
                       const float* __restrict__ loopw, float* __restrict__ Wall) {
    int idx = blockIdx.x * 256 + threadIdx.x;
    if (idx >= 9 * 4096) return;
    int r = idx >> 12, io = idx & 4095;
    float acc;
    if (r < 8) {
        acc = 0.f;
        #pragma unroll
        for (int b = 0; b < 30; ++b) acc += comp[r * 30 + b] * basis[b * 4096 + io];
    } else {
        acc = loopw[io];
    }
    Wall[idx] = acc;
}

// K1: per-(chunk, node-range) packed histogram via LDS atomics.
// part[b][v] = (in_count<<16) | out_count for chunk b.
// NOTE (v8 lesson): global-atomic build is ~10x slower (2M random atomics =
// 87 us). NOTE (v9 lesson): NQ=4/NB=64 regressed +20 us (grid too small,
// 50 KB LDS cut residency). Keep NB=128/NQ=8.
__global__ __launch_bounds__(256) void k_hist2(const int* __restrict__ ei,
                                               uint32* __restrict__ part) {
    __shared__ __align__(16) uint32 h[QN];
    int t = threadIdx.x, b = blockIdx.x, q = blockIdx.y;
    int lo = q * QN;
    int nq = N_NODES - lo; if (nq > QN) nq = QN;
    int4* h4 = (int4*)h;
    for (int i = t; i < QN / 4; i += 256) h4[i] = make_int4(0, 0, 0, 0);
    __syncthreads();
    int e0 = b * CHUNK, e1 = e0 + CHUNK;
    if (e1 > N_EDGES) e1 = N_EDGES;
    for (int e = e0 + t; e < e1; e += 256) {
        int s = ei[e], d = ei[N_EDGES + e];
        unsigned rs = (unsigned)(s - lo), rd = (unsigned)(d - lo);
        if (rs < (unsigned)QN) atomicAdd(&h[rs], 1u);
        if (rd < (unsigned)QN) atomicAdd(&h[rd], 0x10000u);
    }
    __syncthreads();
    int4* d4 = (int4*)(part + b * N_NODES + lo);
    const int4* s4 = (const int4*)h;
    for (int i = t; i < nq / 4; i += 256) d4[i] = s4[i];
}

// K2: degp[v] = sum_b part[b][v]; block sums of deg_in for the scan.
__global__ __launch_bounds__(256) void k_merge(const uint32* __restrict__ part,
                                               uint32* __restrict__ degp,
                                               int* __restrict__ bsum) {
    int t = threadIdx.x, v = blockIdx.x * 256 + t;
    uint32 s = 0;
    if (v < N_NODES) {
        #pragma unroll 8
        for (int b = 0; b < NB; ++b) s += part[b * N_NODES + v];
        degp[v] = s;
    }
    int din = (int)(s >> 16);
    int r = din;
    #pragma unroll
    for (int d = 1; d < 64; d <<= 1) r += __shfl_xor(r, d);
    __shared__ int wsum[4];
    int lane = t & 63, wid = t >> 6;
    if (lane == 0) wsum[wid] = r;
    __syncthreads();
    if (t == 0) bsum[blockIdx.x] = wsum[0] + wsum[1] + wsum[2] + wsum[3];
}

// K3: exclusive scan of 196 block sums (single block).
__global__ void k_scanb(const int* __restrict__ bsum, int* __restrict__ bbase) {
    int t = threadIdx.x;
    int v = (t < NBLK2) ? bsum[t] : 0;
    int lane = t & 63, wid = t >> 6;
    int x = v;
    #pragma unroll
    for (int d = 1; d < 64; d <<= 1) {
        int y = __shfl_up(x, d);
        if (lane >= d) x += y;
    }
    __shared__ int wsum[4];
    if (lane == 63) wsum[wid] = x;
    __syncthreads();
    int base = 0;
    for (int w = 0; w < wid; ++w) base += wsum[w];
    if (t < NBLK2) bbase[t] = base + x - v;
}

// K4: rowptr[v]; convert part[b][v] in-place into fill offsets.
__global__ __launch_bounds__(256) void k_base(uint32* __restrict__ part,
                                              const uint32* __restrict__ degp,
                                              const int* __restrict__ bbase,
                                              int* __restrict__ rowptr) {
    int t = threadIdx.x, v = blockIdx.x * 256 + t;
    int din = (v < N_NODES) ? (int)(degp[v] >> 16) : 0;
    int lane = t & 63, wid = t >> 6;
    int x = din;
    #pragma unroll
    for (int d = 1; d < 64; d <<= 1) {
        int y = __shfl_up(x, d);
        if (lane >= d) x += y;
    }
    __shared__ int wsum[4];
    if (lane == 63) wsum[wid] = x;
    __syncthreads();
    int base = bbase[blockIdx.x];
    for (int w = 0; w < wid; ++w) base += wsum[w];
    int start = base + x - din;
    if (v < N_NODES) {
        rowptr[v] = start;
        if (v == N_NODES - 1) rowptr[N_NODES] = start + din;
        uint32 run = (uint32)start;
        for (int b = 0; b < NB; ++b) {
            uint32 p = part[b * N_NODES + v];
            part[b * N_NODES + v] = run;
            run += (p >> 16);
        }
    }
}

// K5: scatter edges into CSR slots; LDS cursors seeded from fillbase.
__global__ __launch_bounds__(256) void k_fill2(const int* __restrict__ ei,
                                               const int* __restrict__ etype,
                                               const uint32* __restrict__ fillbase,
                                               int2* __restrict__ csr) {
    __shared__ __align__(16) uint32 cur[QN];
    int t = threadIdx.x, b = blockIdx.x, q = blockIdx.y;
    int lo = q * QN;
    int nq = N_NODES - lo; if (nq > QN) nq = QN;
    const int4* s4 = (const int4*)(fillbase + b * N_NODES + lo);
    int4* c4 = (int4*)cur;
    for (int i = t; i < nq / 4; i += 256) c4[i] = s4[i];
    __syncthreads();
    int e0 = b * CHUNK, e1 = e0 + CHUNK;
    if (e1 > N_EDGES) e1 = N_EDGES;
    for (int e = e0 + t; e < e1; e += 256) {
        int d = ei[N_EDGES + e];
        unsigned rd = (unsigned)(d - lo);
        if (rd < (unsigned)QN) {
            int s = ei[e], ty = etype[e];
            uint32 pos = atomicAdd(&cur[rd], 1u);
            csr[pos] = make_int2(s * 9 + ty, s);
        }
    }
}

// K6 (v3 structure, bf16 output): xr16[n][r][64] = bf16(x[n][:] @ Wall[r]).
// 256 nodes x 64 outs per block, 8x8 per-thread tile, K in two 32-wide phases:
// LDS = At[32][256] 32 KB + Wt[32][64] 8 KB = 40 KB.
// DO NOT touch occupancy: 4-phase split inflated VGPR to 136 (107 us, v5);
// launch_bounds(256,6) forced 40 VGPR and spilled acc to scratch (785 us, v6).
// bf16 output halves the 112.5 MB write and halves k_agg1's gather traffic.
__global__ __launch_bounds__(256) void k_xr(const float* __restrict__ x,
                                            const float* __restrict__ Wall,
                                            ushort16* __restrict__ xr) {
    __shared__ __align__(16) float At[32 * 256];   // 32 KB
    __shared__ __align__(16) float Wt[32 * 64];    // 8 KB
    int t = threadIdx.x;
    int n0 = blockIdx.x * 256;
    int r = blockIdx.y;
    int og = t & 7, ng = t >> 3;        // o = og*8 .. +7, nodes = n0 + ng*8 .. +7
    float acc[8][8];
    #pragma unroll
    for (int i = 0; i < 8; ++i)
        #pragma unroll
        for (int j = 0; j < 8; ++j) acc[i][j] = 0.f;

    #pragma unroll
    for (int ph = 0; ph < 2; ++ph) {
        if (ph) __syncthreads();   // all waves done reading phase-0 tiles
        // stage A transposed+swizzled: 256 nodes x 32 k
        #pragma unroll
        for (int j = 0; j < 8; ++j) {
            int f4 = t + j * 256;          // float4 index, < 2048
            int n = f4 >> 3, k4 = f4 & 7;  // 8 float4 per 32-k node row
            float4 v = make_float4(0.f, 0.f, 0.f, 0.f);
            if (n0 + n < N_NODES)
                v = *(const float4*)&x[(n0 + n) * 64 + ph * 32 + k4 * 4];
            int sl = n >> 2, nl = n & 3, kb = k4 * 4;
            At[(kb + 0) * 256 + (((sl ^ ((kb + 0) & 7)) << 2) | nl)] = v.x;
            At[(kb + 1) * 256 + (((sl ^ ((kb + 1) & 7)) << 2) | nl)] = v.y;
            At[(kb + 2) * 256 + (((sl ^ ((kb + 2) & 7)) << 2) | nl)] = v.z;
            At[(kb + 3) * 256 + (((sl ^ ((kb + 3) & 7)) << 2) | nl)] = v.w;
        }
        // stage W (linear copy, conflict-free)
        #pragma unroll
        for (int j = 0; j < 8; ++j) {
            int f = t + j * 256;
            Wt[f] = Wall[r * 4096 + ph * 2048 + f];
        }
        __syncthreads();
        #pragma unroll 4
        for (int k = 0; k < 32; ++k) {
            int c = k & 7;
            float4 aA = *(const float4*)&At[k * 256 + (((2 * ng) ^ c) << 2)];
            float4 aB = *(const float4*)&At[k * 256 + (((2 * ng + 1) ^ c) << 2)];
            float4 w0 = *(const float4*)&Wt[k * 64 + og * 8];
            float4 w1 = *(const float4*)&Wt[k * 64 + og * 8 + 4];
            float a_[8] = {aA.x, aA.y, aA.z, aA.w, aB.x, aB.y, aB.z, aB.w};
            float w_[8] = {w0.x, w0.y, w0.z, w0.w, w1.x, w1.y, w1.z, w1.w};
            #pragma unroll
            for (int i = 0; i < 8; ++i)
                #pragma unroll
                for (int j = 0; j < 8; ++j) acc[i][j] += a_[i] * w_[j];
        }
    }
    #pragma unroll
    for (int i = 0; i < 8; ++i) {
        int n = n0 + ng * 8 + i;
        if (n < N_NODES) {
            uint4 o;
            o.x = (uint32)f2bf(acc[i][0]) | ((uint32)f2bf(acc[i][1]) << 16);
            o.y = (uint32)f2bf(acc[i][2]) | ((uint32)f2bf(acc[i][3]) << 16);
            o.z = (uint32)f2bf(acc[i][4]) | ((uint32)f2bf(acc[i][5]) << 16);
            o.w = (uint32)f2bf(acc[i][6]) | ((uint32)f2bf(acc[i][7]) << 16);
            // 8 bf16 = 16 B, aligned (og*8 ushorts = 16 B multiples)
            *(uint4*)&xr[n * 576 + r * 64 + og * 8] = o;
        }
    }
}

// K7: hs16[v] = bf16((sum_in xr16[csr.x] + xr16[v*9+8] + bias1) * rsqrt(deg_out))
// Gather is 128 B/row (bf16) instead of 256 B — halves the L3-gather pole.
__global__ __launch_bounds__(256) void k_agg1(const ushort16* __restrict__ xr,
                                              const int2* __restrict__ csr,
                                              const int* __restrict__ rowptr,
                                              const uint32* __restrict__ degp,
                                              const float* __restrict__ bias1,
                                              ushort16* __restrict__ hs) {
    int wid = threadIdx.x >> 6, lane = threadIdx.x & 63;
    int v = blockIdx.x * 4 + wid;
    if (v >= N_NODES) return;
    float acc = bf2f(xr[(v * 9 + 8) * 64 + lane]) + bias1[lane];
    int j = rowptr[v], end = rowptr[v + 1];
    for (; j + 4 <= end; j += 4) {
        int r0 = csr[j].x, r1 = csr[j + 1].x, r2 = csr[j + 2].x, r3 = csr[j + 3].x;
        ushort16 a0 = xr[r0 * 64 + lane], a1 = xr[r1 * 64 + lane];
        ushort16 a2 = xr[r2 * 64 + lane], a3 = xr[r3 * 64 + lane];
        acc += bf2f(a0); acc += bf2f(a1); acc += bf2f(a2); acc += bf2f(a3);
    }
    for (; j < end; ++j) acc += bf2f(xr[csr[j].x * 64 + lane]);
    float dg = (float)(degp[v] & 0xffffu);
    if (dg < 1.f) dg = 1.f;
    hs[v * 64 + lane] = f2bf(acc * rsqrtf(dg));
}

// K8a: y2[v] = rsqrt(deg_in[v]) * sum_in hs16[csr.y] — gather only (128 B/row).
// y2 (f32) lives at ws offset 0 (xr16 is dead after k_agg1).
__global__ __launch_bounds__(256) void k_agg2(const ushort16* __restrict__ hs,
                                              const int2* __restrict__ csr,
                                              const int* __restrict__ rowptr,
                                              const uint32* __restrict__ degp,
                                              float* __restrict__ y2) {
    int wid = threadIdx.x >> 6, lane = threadIdx.x & 63;
    int v = blockIdx.x * 4 + wid;
    if (v >= N_NODES) return;
    float acc = 0.f;
    int j = rowptr[v], end = rowptr[v + 1];
    for (; j + 4 <= end; j += 4) {
        int r0 = csr[j].y, r1 = csr[j + 1].y, r2 = csr[j + 2].y, r3 = csr[j + 3].y;
        ushort16 a0 = hs[r0 * 64 + lane], a1 = hs[r1 * 64 + lane];
        ushort16 a2 = hs[r2 * 64 + lane], a3 = hs[r3 * 64 + lane];
        acc += bf2f(a0); acc += bf2f(a1); acc += bf2f(a2); acc += bf2f(a3);
    }
    for (; j < end; ++j) acc += bf2f(hs[csr[j].y * 64 + lane]);
    float dg = (float)(degp[v] >> 16);
    if (dg < 1.f) dg = 1.f;
    y2[v * 64 + lane] = acc * rsqrtf(dg);
}

// K8b: out = y2 @ w2 + bias2 — batched tiled GEMM (f32, v3-k_xr structure).
__global__ __launch_bounds__(256) void k_gemm2(const float* __restrict__ y2,
                                               const float* __restrict__ w2,
                                               const float* __restrict__ bias2,
                                               float* __restrict__ out) {
    __shared__ __align__(16) float At[32 * 256];   // 32 KB
    __shared__ __align__(16) float Wt[32 * 64];    // 8 KB
    int t = threadIdx.x;
    int n0 = blockIdx.x * 256;
    int og = t & 7, ng = t >> 3;
    float acc[8][8];
    #pragma unroll
    for (int i = 0; i < 8; ++i)
        #pragma unroll
        for (int j = 0; j < 8; ++j) acc[i][j] = 0.f;

    #pragma unroll
    for (int ph = 0; ph < 2; ++ph) {
        if (ph) __syncthreads();
        #pragma unroll
        for (int j = 0; j < 8; ++j) {
            int f4 = t + j * 256;
            int n = f4 >> 3, k4 = f4 & 7;
            float4 v = make_float4(0.f, 0.f, 0.f, 0.f);
            if (n0 + n < N_NODES)
                v = *(const float4*)&y2[(n0 + n) * 64 + ph * 32 + k4 * 4];
            int sl = n >> 2, nl = n & 3, kb = k4 * 4;
            At[(kb + 0) * 256 + (((sl ^ ((kb + 0) & 7)) << 2) | nl)] = v.x;
            At[(kb + 1) * 256 + (((sl ^ ((kb + 1) & 7)) << 2) | nl)] = v.y;
            At[(kb + 2) * 256 + (((sl ^ ((kb + 2) & 7)) << 2) | nl)] = v.z;
            At[(kb + 3) * 256 + (((sl ^ ((kb + 3) & 7)) << 2) | nl)] = v.w;
        }
        #pragma unroll
        for (int j = 0; j < 8; ++j) {
            int f = t + j * 256;
            Wt[f] = w2[ph * 2048 + f];
        }
        __syncthreads();
        #pragma unroll 4
        for (int k = 0; k < 32; ++k) {
            int c = k & 7;
            float4 aA = *(const float4*)&At[k * 256 + (((2 * ng) ^ c) << 2)];
            float4 aB = *(const float4*)&At[k * 256 + (((2 * ng + 1) ^ c) << 2)];
            float4 w0 = *(const float4*)&Wt[k * 64 + og * 8];
            float4 w1 = *(const float4*)&Wt[k * 64 + og * 8 + 4];
            float a_[8] = {aA.x, aA.y, aA.z, aA.w, aB.x, aB.y, aB.z, aB.w};
            float w_[8] = {w0.x, w0.y, w0.z, w0.w, w1.x, w1.y, w1.z, w1.w};
            #pragma unroll
            for (int i = 0; i < 8; ++i)
                #pragma unroll
                for (int j = 0; j < 8; ++j) acc[i][j] += a_[i] * w_[j];
        }
    }
    float4 b0 = *(const float4*)&bias2[og * 8];
    float4 b1 = *(const float4*)&bias2[og * 8 + 4];
    #pragma unroll
    for (int i = 0; i < 8; ++i) {
        int n = n0 + ng * 8 + i;
        if (n < N_NODES) {
            *(float4*)&out[n * 64 + og * 8] =
                make_float4(acc[i][0] + b0.x, acc[i][1] + b0.y,
                            acc[i][2] + b0.z, acc[i][3] + b0.w);
            *(float4*)&out[n * 64 + og * 8 + 4] =
                make_float4(acc[i][4] + b1.x, acc[i][5] + b1.y,
                            acc[i][6] + b1.z, acc[i][7] + b1.w);
        }
    }
}

extern "C" void kernel_launch(void* const* d_in, const int* in_sizes, int n_in,
                              void* d_out, int out_size, void* d_ws, size_t ws_size,
                              hipStream_t stream) {
    const float* x      = (const float*)d_in[0];
    const int*   ei     = (const int*)d_in[1];   // [2E]: src then dst
    const int*   etype  = (const int*)d_in[3];
    const float* basis  = (const float*)d_in[4];
    const float* comp   = (const float*)d_in[5];
    const float* loopw  = (const float*)d_in[6];
    const float* bias1  = (const float*)d_in[7];
    const float* w2     = (const float*)d_in[8];
    const float* bias2  = (const float*)d_in[9];
    float* out = (float*)d_out;

    char* ws = (char*)d_ws;
    uint32*   part   = (uint32*)(ws + A_PART);
    ushort16* xr     = (ushort16*)(ws + A_XR);   // aliases part; after fill
    float*    y2     = (float*)(ws + A_Y2);      // aliases xr; after agg1
    uint32*   degp   = (uint32*)(ws + A_DEGP);
    int*      rowptr = (int*)(ws + A_ROWPTR);
    int*      bsum   = (int*)(ws + A_BSUM);
    int*      bbase  = (int*)(ws + A_BBASE);
    int2*     csr    = (int2*)(ws + A_CSR);
    ushort16* hs     = (ushort16*)(ws + A_HS);
    float*    Wall   = (float*)(ws + A_WALL);

    k_wall<<<144, 256, 0, stream>>>(comp, basis, loopw, Wall);
    k_hist2<<<dim3(NB, NQ), 256, 0, stream>>>(ei, part);
    k_merge<<<NBLK2, 256, 0, stream>>>(part, degp, bsum);
    k_scanb<<<1, 256, 0, stream>>>(bsum, bbase);
    k_base<<<NBLK2, 256, 0, stream>>>(part, degp, bbase, rowptr);
    k_fill2<<<dim3(NB, NQ), 256, 0, stream>>>(ei, etype, part, csr);
    k_xr<<<dim3((N_NODES + 255) / 256, 9), 256, 0, stream>>>(x, Wall, xr);
    k_agg1<<<N_NODES / 4, 256, 0, stream>>>(xr, csr, rowptr, degp, bias1, hs);
    k_agg2<<<N_NODES / 4, 256, 0, stream>>>(hs, csr, rowptr, degp, y2);
    k_gemm2<<<(N_NODES + 255) / 256, 256, 0, stream>>>(y2, w2, bias2, out);
}

// Round 11
// 291.355 us; speedup vs baseline: 1.4344x; 1.0111x over previous
//
#include <hip/hip_runtime.h>

#define N_NODES 50000
#define N_EDGES 1000000
#define NB      128         // edge chunks
#define CHUNK   7813        // 128*7813 = 1,000,064 >= E
#define NQ      8           // node ranges per chunk (blockIdx.y)
#define QN      6256        // words per range (16B-aligned); 8*6256 = 50048 >= N
#define NBLK2   196         // ceil(50000/256)

// ---- ws layout (bytes) ----
// Offset 0 is time-shared: part[NB][50000] u32 (25.6 MB, dead after k_fill2)
// -> xr16[50000][9][64] bf16 (57.6 MB, dead after k_agg1)
// -> y2[50000][64] f32 (12.8 MB).
// hs16[50000][64] bf16 (6.4 MB) lives in the old hs slot.
#define A_PART    0
#define A_XR      0
#define A_Y2      0
#define A_DEGP    115200000  // uint[50000] packed: deg_in<<16 | deg_out
#define A_ROWPTR  115400000  // int[50001]
#define A_BSUM    115600128  // int[196]
#define A_BBASE   115601024  // int[196]
#define A_CSR     115601920  // int2[1e6]: (src*9+etype, src)
#define A_HS      123601920  // bf16[50000*64]
#define A_WALL    136401920  // float[9*64*64]  (ends 136,549,376)

typedef unsigned int uint32;
typedef unsigned short ushort16;

// bf16 storage helpers: RNE pack, shift unpack. All math stays fp32.
__device__ inline ushort16 f2bf(float f) {
    uint32 u = __float_as_uint(f);
    return (ushort16)((u + 0x7FFFu + ((u >> 16) & 1u)) >> 16);
}
__device__ inline float bf2f(ushort16 h) {
    return __uint_as_float(((uint32)h) << 16);
}

// K0: Wall[r][i][o] = sum_b comp[r][b]*basis[b][i][o]; Wall[8] = loop_weight
__global__ void k_wall(const float* __restrict__ comp, const float* __restrict__ basis,
                       const float* __restrict__ loopw, float* __restrict__ Wall) {
    int idx = blockIdx.x * 256 + threadIdx.x;
    if (idx >= 9 * 4096) return;
    int r = idx >> 12, io = idx & 4095;
    float acc;
    if (r < 8) {
        acc = 0.f;
        #pragma unroll
        for (int b = 0; b < 30; ++b) acc += comp[r * 30 + b] * basis[b * 4096 + io];
    } else {
        acc = loopw[io];
    }
    Wall[idx] = acc;
}

// K1: per-(chunk, node-range) packed histogram via LDS atomics.
// part[b][v] = (in_count<<16) | out_count for chunk b.
// NOTE (v8 lesson): global-atomic build is ~10x slower (2M random atomics =
// 87 us). NOTE (v9 lesson): NQ=4/NB=64 regressed +20 us (grid too small,
// 50 KB LDS cut residency). Keep NB=128/NQ=8.
__global__ __launch_bounds__(256) void k_hist2(const int* __restrict__ ei,
                                               uint32* __restrict__ part) {
    __shared__ __align__(16) uint32 h[QN];
    int t = threadIdx.x, b = blockIdx.x, q = blockIdx.y;
    int lo = q * QN;
    int nq = N_NODES - lo; if (nq > QN) nq = QN;
    int4* h4 = (int4*)h;
    for (int i = t; i < QN / 4; i += 256) h4[i] = make_int4(0, 0, 0, 0);
    __syncthreads();
    int e0 = b * CHUNK, e1 = e0 + CHUNK;
    if (e1 > N_EDGES) e1 = N_EDGES;
    for (int e = e0 + t; e < e1; e += 256) {
        int s = ei[e], d = ei[N_EDGES + e];
        unsigned rs = (unsigned)(s - lo), rd = (unsigned)(d - lo);
        if (rs < (unsigned)QN) atomicAdd(&h[rs], 1u);
        if (rd < (unsigned)QN) atomicAdd(&h[rd], 0x10000u);
    }
    __syncthreads();
    int4* d4 = (int4*)(part + b * N_NODES + lo);
    const int4* s4 = (const int4*)h;
    for (int i = t; i < nq / 4; i += 256) d4[i] = s4[i];
}

// K2: degp[v] = sum_b part[b][v]; block sums of deg_in for the scan.
__global__ __launch_bounds__(256) void k_merge(const uint32* __restrict__ part,
                                               uint32* __restrict__ degp,
                                               int* __restrict__ bsum) {
    int t = threadIdx.x, v = blockIdx.x * 256 + t;
    uint32 s = 0;
    if (v < N_NODES) {
        #pragma unroll 8
        for (int b = 0; b < NB; ++b) s += part[b * N_NODES + v];
        degp[v] = s;
    }
    int din = (int)(s >> 16);
    int r = din;
    #pragma unroll
    for (int d = 1; d < 64; d <<= 1) r += __shfl_xor(r, d);
    __shared__ int wsum[4];
    int lane = t & 63, wid = t >> 6;
    if (lane == 0) wsum[wid] = r;
    __syncthreads();
    if (t == 0) bsum[blockIdx.x] = wsum[0] + wsum[1] + wsum[2] + wsum[3];
}

// K3: exclusive scan of 196 block sums (single block).
__global__ void k_scanb(const int* __restrict__ bsum, int* __restrict__ bbase) {
    int t = threadIdx.x;
    int v = (t < NBLK2) ? bsum[t] : 0;
    int lane = t & 63, wid = t >> 6;
    int x = v;
    #pragma unroll
    for (int d = 1; d < 64; d <<= 1) {
        int y = __shfl_up(x, d);
        if (lane >= d) x += y;
    }
    __shared__ int wsum[4];
    if (lane == 63) wsum[wid] = x;
    __syncthreads();
    int base = 0;
    for (int w = 0; w < wid; ++w) base += wsum[w];
    if (t < NBLK2) bbase[t] = base + x - v;
}

// K4: rowptr[v]; convert part[b][v] in-place into fill offsets.
__global__ __launch_bounds__(256) void k_base(uint32* __restrict__ part,
                                              const uint32* __restrict__ degp,
                                              const int* __restrict__ bbase,
                                              int* __restrict__ rowptr) {
    int t = threadIdx.x, v = blockIdx.x * 256 + t;
    int din = (v < N_NODES) ? (int)(degp[v] >> 16) : 0;
    int lane = t & 63, wid = t >> 6;
    int x = din;
    #pragma unroll
    for (int d = 1; d < 64; d <<= 1) {
        int y = __shfl_up(x, d);
        if (lane >= d) x += y;
    }
    __shared__ int wsum[4];
    if (lane == 63) wsum[wid] = x;
    __syncthreads();
    int base = bbase[blockIdx.x];
    for (int w = 0; w < wid; ++w) base += wsum[w];
    int start = base + x - din;
    if (v < N_NODES) {
        rowptr[v] = start;
        if (v == N_NODES - 1) rowptr[N_NODES] = start + din;
        uint32 run = (uint32)start;
        for (int b = 0; b < NB; ++b) {
            uint32 p = part[b * N_NODES + v];
            part[b * N_NODES + v] = run;
            run += (p >> 16);
        }
    }
}

// K5: scatter edges into CSR slots; LDS cursors seeded from fillbase.
__global__ __launch_bounds__(256) void k_fill2(const int* __restrict__ ei,
                                               const int* __restrict__ etype,
                                               const uint32* __restrict__ fillbase,
                                               int2* __restrict__ csr) {
    __shared__ __align__(16) uint32 cur[QN];
    int t = threadIdx.x, b = blockIdx.x, q = blockIdx.y;
    int lo = q * QN;
    int nq = N_NODES - lo; if (nq > QN) nq = QN;
    const int4* s4 = (const int4*)(fillbase + b * N_NODES + lo);
    int4* c4 = (int4*)cur;
    for (int i = t; i < nq / 4; i += 256) c4[i] = s4[i];
    __syncthreads();
    int e0 = b * CHUNK, e1 = e0 + CHUNK;
    if (e1 > N_EDGES) e1 = N_EDGES;
    for (int e = e0 + t; e < e1; e += 256) {
        int d = ei[N_EDGES + e];
        unsigned rd = (unsigned)(d - lo);
        if (rd < (unsigned)QN) {
            int s = ei[e], ty = etype[e];
            uint32 pos = atomicAdd(&cur[rd], 1u);
            csr[pos] = make_int2(s * 9 + ty, s);
        }
    }
}

// K6 (v3 structure, bf16 output): xr16[n][r][64] = bf16(x[n][:] @ Wall[r]).
// 256 nodes x 64 outs per block, 8x8 per-thread tile, K in two 32-wide phases:
// LDS = At[32][256] 32 KB + Wt[32][64] 8 KB = 40 KB.
// DO NOT touch occupancy: 4-phase split inflated VGPR to 136 (107 us, v5);
// launch_bounds(256,6) forced 40 VGPR and spilled acc to scratch (785 us, v6).
// bf16 output halves the 112.5 MB write and halves k_agg1's gather traffic.
__global__ __launch_bounds__(256) void k_xr(const float* __restrict__ x,
                                            const float* __restrict__ Wall,
                                            ushort16* __restrict__ xr) {
    __shared__ __align__(16) float At[32 * 256];   // 32 KB
    __shared__ __align__(16) float Wt[32 * 64];    // 8 KB
    int t = threadIdx.x;
    int n0 = blockIdx.x * 256;
    int r = blockIdx.y;
    int og = t & 7, ng = t >> 3;        // o = og*8 .. +7, nodes = n0 + ng*8 .. +7
    float acc[8][8];
    #pragma unroll
    for (int i = 0; i < 8; ++i)
        #pragma unroll
        for (int j = 0; j < 8; ++j) acc[i][j] = 0.f;

    #pragma unroll
    for (int ph = 0; ph < 2; ++ph) {
        if (ph) __syncthreads();   // all waves done reading phase-0 tiles
        // stage A transposed+swizzled: 256 nodes x 32 k
        #pragma unroll
        for (int j = 0; j < 8; ++j) {
            int f4 = t + j * 256;          // float4 index, < 2048
            int n = f4 >> 3, k4 = f4 & 7;  // 8 float4 per 32-k node row
            float4 v = make_float4(0.f, 0.f, 0.f, 0.f);
            if (n0 + n < N_NODES)
                v = *(const float4*)&x[(n0 + n) * 64 + ph * 32 + k4 * 4];
            int sl = n >> 2, nl = n & 3, kb = k4 * 4;
            At[(kb + 0) * 256 + (((sl ^ ((kb + 0) & 7)) << 2) | nl)] = v.x;
            At[(kb + 1) * 256 + (((sl ^ ((kb + 1) & 7)) << 2) | nl)] = v.y;
            At[(kb + 2) * 256 + (((sl ^ ((kb + 2) & 7)) << 2) | nl)] = v.z;
            At[(kb + 3) * 256 + (((sl ^ ((kb + 3) & 7)) << 2) | nl)] = v.w;
        }
        // stage W (linear copy, conflict-free)
        #pragma unroll
        for (int j = 0; j < 8; ++j) {
            int f = t + j * 256;
            Wt[f] = Wall[r * 4096 + ph * 2048 + f];
        }
        __syncthreads();
        #pragma unroll 4
        for (int k = 0; k < 32; ++k) {
            int c = k & 7;
            float4 aA = *(const float4*)&At[k * 256 + (((2 * ng) ^ c) << 2)];
            float4 aB = *(const float4*)&At[k * 256 + (((2 * ng + 1) ^ c) << 2)];
            float4 w0 = *(const float4*)&Wt[k * 64 + og * 8];
            float4 w1 = *(const float4*)&Wt[k * 64 + og * 8 + 4];
            float a_[8] = {aA.x, aA.y, aA.z, aA.w, aB.x, aB.y, aB.z, aB.w};
            float w_[8] = {w0.x, w0.y, w0.z, w0.w, w1.x, w1.y, w1.z, w1.w};
            #pragma unroll
            for (int i = 0; i < 8; ++i)
                #pragma unroll
                for (int j = 0; j < 8; ++j) acc[i][j] += a_[i] * w_[j];
        }
    }
    #pragma unroll
    for (int i = 0; i < 8; ++i) {
        int n = n0 + ng * 8 + i;
        if (n < N_NODES) {
            uint4 o;
            o.x = (uint32)f2bf(acc[i][0]) | ((uint32)f2bf(acc[i][1]) << 16);
            o.y = (uint32)f2bf(acc[i][2]) | ((uint32)f2bf(acc[i][3]) << 16);
            o.z = (uint32)f2bf(acc[i][4]) | ((uint32)f2bf(acc[i][5]) << 16);
            o.w = (uint32)f2bf(acc[i][6]) | ((uint32)f2bf(acc[i][7]) << 16);
            // 8 bf16 = 16 B, aligned (og*8 ushorts = 16 B multiples)
            *(uint4*)&xr[n * 576 + r * 64 + og * 8] = o;
        }
    }
}

// K7 v11: wide gather — 4 CSR rows per VMEM instruction.
// lane = sub*16 + cg: sub picks row j+sub, cg picks channels [4cg,4cg+4)
// loaded as one uint2 (4 bf16, 8 B). 64 lanes x 8 B = 512 B/instr = 4 rows
// (v10: 1 row/instr at 2 B/lane — VMEM-issue bound). Butterfly shfl_xor(16,32)
// merges the 4 sub-partials; sub==0 lanes write the row.
__global__ __launch_bounds__(256) void k_agg1(const ushort16* __restrict__ xr,
                                              const int2* __restrict__ csr,
                                              const int* __restrict__ rowptr,
                                              const uint32* __restrict__ degp,
                                              const float* __restrict__ bias1,
                                              ushort16* __restrict__ hs) {
    int t = threadIdx.x;
    int wid = t >> 6, lane = t & 63;
    int v = blockIdx.x * 4 + wid;
    if (v >= N_NODES) return;
    int sub = lane >> 4, cg = lane & 15;
    float a0 = 0.f, a1 = 0.f, a2 = 0.f, a3 = 0.f;
    int end = rowptr[v + 1];
    for (int j = rowptr[v] + sub; j < end; j += 4) {
        int r0 = csr[j].x;
        uint2 u = *(const uint2*)&xr[r0 * 64 + cg * 4];
        a0 += __uint_as_float(u.x << 16);
        a1 += __uint_as_float(u.x & 0xffff0000u);
        a2 += __uint_as_float(u.y << 16);
        a3 += __uint_as_float(u.y & 0xffff0000u);
    }
    #pragma unroll
    for (int d = 16; d < 64; d <<= 1) {
        a0 += __shfl_xor(a0, d);
        a1 += __shfl_xor(a1, d);
        a2 += __shfl_xor(a2, d);
        a3 += __shfl_xor(a3, d);
    }
    // self-loop + bias (after reduce: counted once; all lanes hold the total)
    uint2 slu = *(const uint2*)&xr[(v * 9 + 8) * 64 + cg * 4];
    float4 b = *(const float4*)&bias1[cg * 4];
    a0 += __uint_as_float(slu.x << 16) + b.x;
    a1 += __uint_as_float(slu.x & 0xffff0000u) + b.y;
    a2 += __uint_as_float(slu.y << 16) + b.z;
    a3 += __uint_as_float(slu.y & 0xffff0000u) + b.w;
    float dg = (float)(degp[v] & 0xffffu);
    if (dg < 1.f) dg = 1.f;
    float s = rsqrtf(dg);
    if (sub == 0) {
        uint2 o;
        o.x = (uint32)f2bf(a0 * s) | ((uint32)f2bf(a1 * s) << 16);
        o.y = (uint32)f2bf(a2 * s) | ((uint32)f2bf(a3 * s) << 16);
        *(uint2*)&hs[v * 64 + cg * 4] = o;
    }
}

// K8a v11: same wide-gather structure over hs16 (csr.y); f32 output to y2.
__global__ __launch_bounds__(256) void k_agg2(const ushort16* __restrict__ hs,
                                              const int2* __restrict__ csr,
                                              const int* __restrict__ rowptr,
                                              const uint32* __restrict__ degp,
                                              float* __restrict__ y2) {
    int t = threadIdx.x;
    int wid = t >> 6, lane = t & 63;
    int v = blockIdx.x * 4 + wid;
    if (v >= N_NODES) return;
    int sub = lane >> 4, cg = lane & 15;
    float a0 = 0.f, a1 = 0.f, a2 = 0.f, a3 = 0.f;
    int end = rowptr[v + 1];
    for (int j = rowptr[v] + sub; j < end; j += 4) {
        int r0 = csr[j].y;
        uint2 u = *(const uint2*)&hs[r0 * 64 + cg * 4];
        a0 += __uint_as_float(u.x << 16);
        a1 += __uint_as_float(u.x & 0xffff0000u);
        a2 += __uint_as_float(u.y << 16);
        a3 += __uint_as_float(u.y & 0xffff0000u);
    }
    #pragma unroll
    for (int d = 16; d < 64; d <<= 1) {
        a0 += __shfl_xor(a0, d);
        a1 += __shfl_xor(a1, d);
        a2 += __shfl_xor(a2, d);
        a3 += __shfl_xor(a3, d);
    }
    float dg = (float)(degp[v] >> 16);
    if (dg < 1.f) dg = 1.f;
    float s = rsqrtf(dg);
    if (sub == 0) {
        *(float4*)&y2[v * 64 + cg * 4] =
            make_float4(a0 * s, a1 * s, a2 * s, a3 * s);
    }
}

// K8b: out = y2 @ w2 + bias2 — batched tiled GEMM (f32, v3-k_xr structure).
__global__ __launch_bounds__(256) void k_gemm2(const float* __restrict__ y2,
                                               const float* __restrict__ w2,
                                               const float* __restrict__ bias2,
                                               float* __restrict__ out) {
    __shared__ __align__(16) float At[32 * 256];   // 32 KB
    __shared__ __align__(16) float Wt[32 * 64];    // 8 KB
    int t = threadIdx.x;
    int n0 = blockIdx.x * 256;
    int og = t & 7, ng = t >> 3;
    float acc[8][8];
    #pragma unroll
    for (int i = 0; i < 8; ++i)
        #pragma unroll
        for (int j = 0; j < 8; ++j) acc[i][j] = 0.f;

    #pragma unroll
    for (int ph = 0; ph < 2; ++ph) {
        if (ph) __syncthreads();
        #pragma unroll
        for (int j = 0; j < 8; ++j) {
            int f4 = t + j * 256;
            int n = f4 >> 3, k4 = f4 & 7;
            float4 v = make_float4(0.f, 0.f, 0.f, 0.f);
            if (n0 + n < N_NODES)
                v = *(const float4*)&y2[(n0 + n) * 64 + ph * 32 + k4 * 4];
            int sl = n >> 2, nl = n & 3, kb = k4 * 4;
            At[(kb + 0) * 256 + (((sl ^ ((kb + 0) & 7)) << 2) | nl)] = v.x;
            At[(kb + 1) * 256 + (((sl ^ ((kb + 1) & 7)) << 2) | nl)] = v.y;
            At[(kb + 2) * 256 + (((sl ^ ((kb + 2) & 7)) << 2) | nl)] = v.z;
            At[(kb + 3) * 256 + (((sl ^ ((kb + 3) & 7)) << 2) | nl)] = v.w;
        }
        #pragma unroll
        for (int j = 0; j < 8; ++j) {
            int f = t + j * 256;
            Wt[f] = w2[ph * 2048 + f];
        }
        __syncthreads();
        #pragma unroll 4
        for (int k = 0; k < 32; ++k) {
            int c = k & 7;
            float4 aA = *(const float4*)&At[k * 256 + (((2 * ng) ^ c) << 2)];
            float4 aB = *(const float4*)&At[k * 256 + (((2 * ng + 1) ^ c) << 2)];
            float4 w0 = *(const float4*)&Wt[k * 64 + og * 8];
            float4 w1 = *(const float4*)&Wt[k * 64 + og * 8 + 4];
            float a_[8] = {aA.x, aA.y, aA.z, aA.w, aB.x, aB.y, aB.z, aB.w};
            float w_[8] = {w0.x, w0.y, w0.z, w0.w, w1.x, w1.y, w1.z, w1.w};
            #pragma unroll
            for (int i = 0; i < 8; ++i)
                #pragma unroll
                for (int j = 0; j < 8; ++j) acc[i][j] += a_[i] * w_[j];
        }
    }
    float4 b0 = *(const float4*)&bias2[og * 8];
    float4 b1 = *(const float4*)&bias2[og * 8 + 4];
    #pragma unroll
    for (int i = 0; i < 8; ++i) {
        int n = n0 + ng * 8 + i;
        if (n < N_NODES) {
            *(float4*)&out[n * 64 + og * 8] =
                make_float4(acc[i][0] + b0.x, acc[i][1] + b0.y,
                            acc[i][2] + b0.z, acc[i][3] + b0.w);
            *(float4*)&out[n * 64 + og * 8 + 4] =
                make_float4(acc[i][4] + b1.x, acc[i][5] + b1.y,
                            acc[i][6] + b1.z, acc[i][7] + b1.w);
        }
    }
}

extern "C" void kernel_launch(void* const* d_in, const int* in_sizes, int n_in,
                              void* d_out, int out_size, void* d_ws, size_t ws_size,
                              hipStream_t stream) {
    const float* x      = (const float*)d_in[0];
    const int*   ei     = (const int*)d_in[1];   // [2E]: src then dst
    const int*   etype  = (const int*)d_in[3];
    const float* basis  = (const float*)d_in[4];
    const float* comp   = (const float*)d_in[5];
    const float* loopw  = (const float*)d_in[6];
    const float* bias1  = (const float*)d_in[7];
    const float* w2     = (const float*)d_in[8];
    const float* bias2  = (const float*)d_in[9];
    float* out = (float*)d_out;

    char* ws = (char*)d_ws;
    uint32*   part   = (uint32*)(ws + A_PART);
    ushort16* xr     = (ushort16*)(ws + A_XR);   // aliases part; after fill
    float*    y2     = (float*)(ws + A_Y2);      // aliases xr; after agg1
    uint32*   degp   = (uint32*)(ws + A_DEGP);
    int*      rowptr = (int*)(ws + A_ROWPTR);
    int*      bsum   = (int*)(ws + A_BSUM);
    int*      bbase  = (int*)(ws + A_BBASE);
    int2*     csr    = (int2*)(ws + A_CSR);
    ushort16* hs     = (ushort16*)(ws + A_HS);
    float*    Wall   = (float*)(ws + A_WALL);

    k_wall<<<144, 256, 0, stream>>>(comp, basis, loopw, Wall);
    k_hist2<<<dim3(NB, NQ), 256, 0, stream>>>(ei, part);
    k_merge<<<NBLK2, 256, 0, stream>>>(part, degp, bsum);
    k_scanb<<<1, 256, 0, stream>>>(bsum, bbase);
    k_base<<<NBLK2, 256, 0, stream>>>(part, degp, bbase, rowptr);
    k_fill2<<<dim3(NB, NQ), 256, 0, stream>>>(ei, etype, part, csr);
    k_xr<<<dim3((N_NODES + 255) / 256, 9), 256, 0, stream>>>(x, Wall, xr);
    k_agg1<<<N_NODES / 4, 256, 0, stream>>>(xr, csr, rowptr, degp, bias1, hs);
    k_agg2<<<N_NODES / 4, 256, 0, stream>>>(hs, csr, rowptr, degp, y2);
    k_gemm2<<<(N_NODES + 255) / 256, 256, 0, stream>>>(y2, w2, bias2, out);
}

// Round 12
// 260.534 us; speedup vs baseline: 1.6040x; 1.1183x over previous
//
#include <hip/hip_runtime.h>

#define N_NODES 50000
#define N_EDGES 1000000
#define NB      128         // edge chunks
#define CHUNK   7813        // 128*7813 = 1,000,064 >= E
#define NQ      8           // node ranges per chunk (blockIdx.y)
#define QN      6256        // words per range (16B-aligned); 8*6256 = 50048 >= N
#define NBLK2   196         // ceil(50000/256)

// ---- ws layout (bytes) ----
// Offset 0 is time-shared: part[NB][50000] u32 (25.6 MB, dead after k_fill2)
// -> xr16[50000][9][64] bf16 (57.6 MB, dead after k_agg1)
// -> y2[50000][64] f32 (12.8 MB).
// xbf[50000][64] bf16 (6.4 MB) at 57.6 MB (free hole at all times).
// hs16[50000][64] bf16 (6.4 MB) in the old hs slot.
#define A_PART    0
#define A_XR      0
#define A_Y2      0
#define A_XBF     57600000
#define A_DEGP    115200000  // uint[50000] packed: deg_in<<16 | deg_out
#define A_ROWPTR  115400000  // int[50001]
#define A_BSUM    115600128  // int[196]
#define A_BBASE   115601024  // int[196]
#define A_CSR     115601920  // int2[1e6]: (src*9+etype, src)
#define A_HS      123601920  // bf16[50000*64]
#define A_WALL    136401920  // bf16[9*64*64] transposed [r][o][k]
typedef unsigned int uint32;
typedef unsigned short ushort16;
typedef __attribute__((ext_vector_type(8))) short bf16x8;
typedef __attribute__((ext_vector_type(4))) float f32x4;

// bf16 storage helpers: RNE pack, shift unpack. All math stays fp32.
__device__ inline ushort16 f2bf(float f) {
    uint32 u = __float_as_uint(f);
    return (ushort16)((u + 0x7FFFu + ((u >> 16) & 1u)) >> 16);
}
__device__ inline float bf2f(ushort16 h) {
    return __uint_as_float(((uint32)h) << 16);
}

// K0: wallbf[r][o][i] = bf16(sum_b comp[r][b]*basis[b][i][o]); r=8 -> loopw.
// Transposed (o-major) so k_xr's MFMA B-fragments read contiguous k.
__global__ void k_wall(const float* __restrict__ comp, const float* __restrict__ basis,
                       const float* __restrict__ loopw, ushort16* __restrict__ wallbf) {
    int idx = blockIdx.x * 256 + threadIdx.x;
    if (idx >= 9 * 4096) return;
    int r = idx >> 12, io = idx & 4095;
    int i = io >> 6, o = io & 63;
    float acc;
    if (r < 8) {
        acc = 0.f;
        #pragma unroll
        for (int b = 0; b < 30; ++b) acc += comp[r * 30 + b] * basis[b * 4096 + io];
    } else {
        acc = loopw[io];
    }
    wallbf[r * 4096 + o * 64 + i] = f2bf(acc);
}

// K0b: xbf = bf16(x), 8 elements/thread.
__global__ __launch_bounds__(256) void k_xbf(const float* __restrict__ x,
                                             ushort16* __restrict__ xbf) {
    int g = blockIdx.x * 256 + threadIdx.x;
    int base = g * 8;
    if (base >= N_NODES * 64) return;
    float4 v0 = *(const float4*)&x[base];
    float4 v1 = *(const float4*)&x[base + 4];
    uint4 o;
    o.x = (uint32)f2bf(v0.x) | ((uint32)f2bf(v0.y) << 16);
    o.y = (uint32)f2bf(v0.z) | ((uint32)f2bf(v0.w) << 16);
    o.z = (uint32)f2bf(v1.x) | ((uint32)f2bf(v1.y) << 16);
    o.w = (uint32)f2bf(v1.z) | ((uint32)f2bf(v1.w) << 16);
    *(uint4*)&xbf[base] = o;
}

// K1: per-(chunk, node-range) packed histogram via LDS atomics.
// part[b][v] = (in_count<<16) | out_count for chunk b.
// NOTE (v8 lesson): global-atomic build is ~10x slower (2M random atomics =
// 87 us). NOTE (v9 lesson): NQ=4/NB=64 regressed +20 us. Keep NB=128/NQ=8.
__global__ __launch_bounds__(256) void k_hist2(const int* __restrict__ ei,
                                               uint32* __restrict__ part) {
    __shared__ __align__(16) uint32 h[QN];
    int t = threadIdx.x, b = blockIdx.x, q = blockIdx.y;
    int lo = q * QN;
    int nq = N_NODES - lo; if (nq > QN) nq = QN;
    int4* h4 = (int4*)h;
    for (int i = t; i < QN / 4; i += 256) h4[i] = make_int4(0, 0, 0, 0);
    __syncthreads();
    int e0 = b * CHUNK, e1 = e0 + CHUNK;
    if (e1 > N_EDGES) e1 = N_EDGES;
    for (int e = e0 + t; e < e1; e += 256) {
        int s = ei[e], d = ei[N_EDGES + e];
        unsigned rs = (unsigned)(s - lo), rd = (unsigned)(d - lo);
        if (rs < (unsigned)QN) atomicAdd(&h[rs], 1u);
        if (rd < (unsigned)QN) atomicAdd(&h[rd], 0x10000u);
    }
    __syncthreads();
    int4* d4 = (int4*)(part + b * N_NODES + lo);
    const int4* s4 = (const int4*)h;
    for (int i = t; i < nq / 4; i += 256) d4[i] = s4[i];
}

// K2: degp[v] = sum_b part[b][v]; block sums of deg_in for the scan.
__global__ __launch_bounds__(256) void k_merge(const uint32* __restrict__ part,
                                               uint32* __restrict__ degp,
                                               int* __restrict__ bsum) {
    int t = threadIdx.x, v = blockIdx.x * 256 + t;
    uint32 s = 0;
    if (v < N_NODES) {
        #pragma unroll 8
        for (int b = 0; b < NB; ++b) s += part[b * N_NODES + v];
        degp[v] = s;
    }
    int din = (int)(s >> 16);
    int r = din;
    #pragma unroll
    for (int d = 1; d < 64; d <<= 1) r += __shfl_xor(r, d);
    __shared__ int wsum[4];
    int lane = t & 63, wid = t >> 6;
    if (lane == 0) wsum[wid] = r;
    __syncthreads();
    if (t == 0) bsum[blockIdx.x] = wsum[0] + wsum[1] + wsum[2] + wsum[3];
}

// K3: exclusive scan of 196 block sums (single block).
__global__ void k_scanb(const int* __restrict__ bsum, int* __restrict__ bbase) {
    int t = threadIdx.x;
    int v = (t < NBLK2) ? bsum[t] : 0;
    int lane = t & 63, wid = t >> 6;
    int x = v;
    #pragma unroll
    for (int d = 1; d < 64; d <<= 1) {
        int y = __shfl_up(x, d);
        if (lane >= d) x += y;
    }
    __shared__ int wsum[4];
    if (lane == 63) wsum[wid] = x;
    __syncthreads();
    int base = 0;
    for (int w = 0; w < wid; ++w) base += wsum[w];
    if (t < NBLK2) bbase[t] = base + x - v;
}

// K4: rowptr[v]; convert part[b][v] in-place into fill offsets.
__global__ __launch_bounds__(256) void k_base(uint32* __restrict__ part,
                                              const uint32* __restrict__ degp,
                                              const int* __restrict__ bbase,
                                              int* __restrict__ rowptr) {
    int t = threadIdx.x, v = blockIdx.x * 256 + t;
    int din = (v < N_NODES) ? (int)(degp[v] >> 16) : 0;
    int lane = t & 63, wid = t >> 6;
    int x = din;
    #pragma unroll
    for (int d = 1; d < 64; d <<= 1) {
        int y = __shfl_up(x, d);
        if (lane >= d) x += y;
    }
    __shared__ int wsum[4];
    if (lane == 63) wsum[wid] = x;
    __syncthreads();
    int base = bbase[blockIdx.x];
    for (int w = 0; w < wid; ++w) base += wsum[w];
    int start = base + x - din;
    if (v < N_NODES) {
        rowptr[v] = start;
        if (v == N_NODES - 1) rowptr[N_NODES] = start + din;
        uint32 run = (uint32)start;
        for (int b = 0; b < NB; ++b) {
            uint32 p = part[b * N_NODES + v];
            part[b * N_NODES + v] = run;
            run += (p >> 16);
        }
    }
}

// K5: scatter edges into CSR slots; LDS cursors seeded from fillbase.
__global__ __launch_bounds__(256) void k_fill2(const int* __restrict__ ei,
                                               const int* __restrict__ etype,
                                               const uint32* __restrict__ fillbase,
                                               int2* __restrict__ csr) {
    __shared__ __align__(16) uint32 cur[QN];
    int t = threadIdx.x, b = blockIdx.x, q = blockIdx.y;
    int lo = q * QN;
    int nq = N_NODES - lo; if (nq > QN) nq = QN;
    const int4* s4 = (const int4*)(fillbase + b * N_NODES + lo);
    int4* c4 = (int4*)cur;
    for (int i = t; i < nq / 4; i += 256) c4[i] = s4[i];
    __syncthreads();
    int e0 = b * CHUNK, e1 = e0 + CHUNK;
    if (e1 > N_EDGES) e1 = N_EDGES;
    for (int e = e0 + t; e < e1; e += 256) {
        int d = ei[N_EDGES + e];
        unsigned rd = (unsigned)(d - lo);
        if (rd < (unsigned)QN) {
            int s = ei[e], ty = etype[e];
            uint32 pos = atomicAdd(&cur[rd], 1u);
            csr[pos] = make_int2(s * 9 + ty, s);
        }
    }
}

// K6 v12: xr via bf16 MFMA (mfma_f32_16x16x32_bf16).
// Block = 64 nodes x 64 outs x 1 relation, 4 waves; wave w owns node rows
// [w*16, w*16+16), iterates 4 col-tiles x 2 k-halves = 8 MFMA.
// LDS: Abf[64 n][64 k] bf16 + Wbf[64 o][64 k] bf16 (both with 16B-slot XOR
// swizzle: slot s of row n stored at s^(n&7) -> frag ds_read_b128 at the
// 8-phase wave floor, no extra conflicts) + Ot[64][64] bf16 repack = 24 KB.
// Frag layouts (cdna4_isa $10, m89): A/B lane l: row/col = l&15, k = (l>>4)*8+j;
// D: col = l&15, row = (l>>4)*4 + j.
__global__ __launch_bounds__(256) void k_xr(const ushort16* __restrict__ xbf,
                                            const ushort16* __restrict__ wallbf,
                                            ushort16* __restrict__ xr) {
    __shared__ __align__(16) ushort16 Abf[64 * 64];
    __shared__ __align__(16) ushort16 Wbf[64 * 64];
    __shared__ __align__(16) ushort16 Ot[64 * 64];
    int t = threadIdx.x;
    int n0 = blockIdx.x * 64;
    int r = blockIdx.y;
    {   // stage A and W: row n = t>>2, slots s0, s0+1 (16 B each)
        int n = t >> 2, s0 = (t & 3) * 2;
        uint4 v0 = make_uint4(0, 0, 0, 0), v1 = v0;
        if (n0 + n < N_NODES) {
            v0 = *(const uint4*)&xbf[(n0 + n) * 64 + s0 * 8];
            v1 = *(const uint4*)&xbf[(n0 + n) * 64 + s0 * 8 + 8];
        }
        *(uint4*)&Abf[n * 64 + ((s0 ^ (n & 7)) * 8)]       = v0;
        *(uint4*)&Abf[n * 64 + (((s0 + 1) ^ (n & 7)) * 8)] = v1;
        uint4 w0 = *(const uint4*)&wallbf[r * 4096 + n * 64 + s0 * 8];
        uint4 w1 = *(const uint4*)&wallbf[r * 4096 + n * 64 + s0 * 8 + 8];
        *(uint4*)&Wbf[n * 64 + ((s0 ^ (n & 7)) * 8)]       = w0;
        *(uint4*)&Wbf[n * 64 + (((s0 + 1) ^ (n & 7)) * 8)] = w1;
    }
    __syncthreads();
    int w = t >> 6, l = t & 63;
    int row = l & 15, kg = l >> 4;          // frag row/col and k-group
    int an = w * 16 + row;
    bf16x8 a0 = *(const bf16x8*)&Abf[an * 64 + (((0 + kg) ^ (an & 7)) * 8)];
    bf16x8 a1 = *(const bf16x8*)&Abf[an * 64 + (((4 + kg) ^ (an & 7)) * 8)];
    #pragma unroll
    for (int ct = 0; ct < 4; ++ct) {
        int bo = ct * 16 + row;
        bf16x8 b0 = *(const bf16x8*)&Wbf[bo * 64 + (((0 + kg) ^ (bo & 7)) * 8)];
        bf16x8 b1 = *(const bf16x8*)&Wbf[bo * 64 + (((4 + kg) ^ (bo & 7)) * 8)];
        f32x4 acc = {0.f, 0.f, 0.f, 0.f};
        acc = __builtin_amdgcn_mfma_f32_16x16x32_bf16(a0, b0, acc, 0, 0, 0);
        acc = __builtin_amdgcn_mfma_f32_16x16x32_bf16(a1, b1, acc, 0, 0, 0);
        #pragma unroll
        for (int j = 0; j < 4; ++j)
            Ot[(w * 16 + kg * 4 + j) * 64 + ct * 16 + row] = f2bf(acc[j]);
    }
    __syncthreads();
    {   // copyout to xr[n][r*64 + o], vectorized
        int n = t >> 2, s = (t & 3) * 2;
        if (n0 + n < N_NODES) {
            *(uint4*)&xr[(n0 + n) * 576 + r * 64 + s * 8] =
                *(const uint4*)&Ot[n * 64 + s * 8];
            *(uint4*)&xr[(n0 + n) * 576 + r * 64 + s * 8 + 8] =
                *(const uint4*)&Ot[n * 64 + s * 8 + 8];
        }
    }
}

// K7 v11: wide gather — 4 CSR rows per VMEM instruction.
__global__ __launch_bounds__(256) void k_agg1(const ushort16* __restrict__ xr,
                                              const int2* __restrict__ csr,
                                              const int* __restrict__ rowptr,
                                              const uint32* __restrict__ degp,
                                              const float* __restrict__ bias1,
                                              ushort16* __restrict__ hs) {
    int t = threadIdx.x;
    int wid = t >> 6, lane = t & 63;
    int v = blockIdx.x * 4 + wid;
    if (v >= N_NODES) return;
    int sub = lane >> 4, cg = lane & 15;
    float a0 = 0.f, a1 = 0.f, a2 = 0.f, a3 = 0.f;
    int end = rowptr[v + 1];
    for (int j = rowptr[v] + sub; j < end; j += 4) {
        int r0 = csr[j].x;
        uint2 u = *(const uint2*)&xr[r0 * 64 + cg * 4];
        a0 += __uint_as_float(u.x << 16);
        a1 += __uint_as_float(u.x & 0xffff0000u);
        a2 += __uint_as_float(u.y << 16);
        a3 += __uint_as_float(u.y & 0xffff0000u);
    }
    #pragma unroll
    for (int d = 16; d < 64; d <<= 1) {
        a0 += __shfl_xor(a0, d);
        a1 += __shfl_xor(a1, d);
        a2 += __shfl_xor(a2, d);
        a3 += __shfl_xor(a3, d);
    }
    uint2 slu = *(const uint2*)&xr[(v * 9 + 8) * 64 + cg * 4];
    float4 b = *(const float4*)&bias1[cg * 4];
    a0 += __uint_as_float(slu.x << 16) + b.x;
    a1 += __uint_as_float(slu.x & 0xffff0000u) + b.y;
    a2 += __uint_as_float(slu.y << 16) + b.z;
    a3 += __uint_as_float(slu.y & 0xffff0000u) + b.w;
    float dg = (float)(degp[v] & 0xffffu);
    if (dg < 1.f) dg = 1.f;
    float s = rsqrtf(dg);
    if (sub == 0) {
        uint2 o;
        o.x = (uint32)f2bf(a0 * s) | ((uint32)f2bf(a1 * s) << 16);
        o.y = (uint32)f2bf(a2 * s) | ((uint32)f2bf(a3 * s) << 16);
        *(uint2*)&hs[v * 64 + cg * 4] = o;
    }
}

// K8a v11: same wide-gather structure over hs16 (csr.y); f32 output to y2.
__global__ __launch_bounds__(256) void k_agg2(const ushort16* __restrict__ hs,
                                              const int2* __restrict__ csr,
                                              const int* __restrict__ rowptr,
                                              const uint32* __restrict__ degp,
                                              float* __restrict__ y2) {
    int t = threadIdx.x;
    int wid = t >> 6, lane = t & 63;
    int v = blockIdx.x * 4 + wid;
    if (v >= N_NODES) return;
    int sub = lane >> 4, cg = lane & 15;
    float a0 = 0.f, a1 = 0.f, a2 = 0.f, a3 = 0.f;
    int end = rowptr[v + 1];
    for (int j = rowptr[v] + sub; j < end; j += 4) {
        int r0 = csr[j].y;
        uint2 u = *(const uint2*)&hs[r0 * 64 + cg * 4];
        a0 += __uint_as_float(u.x << 16);
        a1 += __uint_as_float(u.x & 0xffff0000u);
        a2 += __uint_as_float(u.y << 16);
        a3 += __uint_as_float(u.y & 0xffff0000u);
    }
    #pragma unroll
    for (int d = 16; d < 64; d <<= 1) {
        a0 += __shfl_xor(a0, d);
        a1 += __shfl_xor(a1, d);
        a2 += __shfl_xor(a2, d);
        a3 += __shfl_xor(a3, d);
    }
    float dg = (float)(degp[v] >> 16);
    if (dg < 1.f) dg = 1.f;
    float s = rsqrtf(dg);
    if (sub == 0) {
        *(float4*)&y2[v * 64 + cg * 4] =
            make_float4(a0 * s, a1 * s, a2 * s, a3 * s);
    }
}

// K8b: out = y2 @ w2 + bias2 — batched tiled GEMM (f32, v3-k_xr structure).
__global__ __launch_bounds__(256) void k_gemm2(const float* __restrict__ y2,
                                               const float* __restrict__ w2,
                                               const float* __restrict__ bias2,
                                               float* __restrict__ out) {
    __shared__ __align__(16) float At[32 * 256];   // 32 KB
    __shared__ __align__(16) float Wt[32 * 64];    // 8 KB
    int t = threadIdx.x;
    int n0 = blockIdx.x * 256;
    int og = t & 7, ng = t >> 3;
    float acc[8][8];
    #pragma unroll
    for (int i = 0; i < 8; ++i)
        #pragma unroll
        for (int j = 0; j < 8; ++j) acc[i][j] = 0.f;

    #pragma unroll
    for (int ph = 0; ph < 2; ++ph) {
        if (ph) __syncthreads();
        #pragma unroll
        for (int j = 0; j < 8; ++j) {
            int f4 = t + j * 256;
            int n = f4 >> 3, k4 = f4 & 7;
            float4 v = make_float4(0.f, 0.f, 0.f, 0.f);
            if (n0 + n < N_NODES)
                v = *(const float4*)&y2[(n0 + n) * 64 + ph * 32 + k4 * 4];
            int sl = n >> 2, nl = n & 3, kb = k4 * 4;
            At[(kb + 0) * 256 + (((sl ^ ((kb + 0) & 7)) << 2) | nl)] = v.x;
            At[(kb + 1) * 256 + (((sl ^ ((kb + 1) & 7)) << 2) | nl)] = v.y;
            At[(kb + 2) * 256 + (((sl ^ ((kb + 2) & 7)) << 2) | nl)] = v.z;
            At[(kb + 3) * 256 + (((sl ^ ((kb + 3) & 7)) << 2) | nl)] = v.w;
        }
        #pragma unroll
        for (int j = 0; j < 8; ++j) {
            int f = t + j * 256;
            Wt[f] = w2[ph * 2048 + f];
        }
        __syncthreads();
        #pragma unroll 4
        for (int k = 0; k < 32; ++k) {
            int c = k & 7;
            float4 aA = *(const float4*)&At[k * 256 + (((2 * ng) ^ c) << 2)];
            float4 aB = *(const float4*)&At[k * 256 + (((2 * ng + 1) ^ c) << 2)];
            float4 w0 = *(const float4*)&Wt[k * 64 + og * 8];
            float4 w1 = *(const float4*)&Wt[k * 64 + og * 8 + 4];
            float a_[8] = {aA.x, aA.y, aA.z, aA.w, aB.x, aB.y, aB.z, aB.w};
            float w_[8] = {w0.x, w0.y, w0.z, w0.w, w1.x, w1.y, w1.z, w1.w};
            #pragma unroll
            for (int i = 0; i < 8; ++i)
                #pragma unroll
                for (int j = 0; j < 8; ++j) acc[i][j] += a_[i] * w_[j];
        }
    }
    float4 b0 = *(const float4*)&bias2[og * 8];
    float4 b1 = *(const float4*)&bias2[og * 8 + 4];
    #pragma unroll
    for (int i = 0; i < 8; ++i) {
        int n = n0 + ng * 8 + i;
        if (n < N_NODES) {
            *(float4*)&out[n * 64 + og * 8] =
                make_float4(acc[i][0] + b0.x, acc[i][1] + b0.y,
                            acc[i][2] + b0.z, acc[i][3] + b0.w);
            *(float4*)&out[n * 64 + og * 8 + 4] =
                make_float4(acc[i][4] + b1.x, acc[i][5] + b1.y,
                            acc[i][6] + b1.z, acc[i][7] + b1.w);
        }
    }
}

extern "C" void kernel_launch(void* const* d_in, const int* in_sizes, int n_in,
                              void* d_out, int out_size, void* d_ws, size_t ws_size,
                              hipStream_t stream) {
    const float* x      = (const float*)d_in[0];
    const int*   ei     = (const int*)d_in[1];   // [2E]: src then dst
    const int*   etype  = (const int*)d_in[3];
    const float* basis  = (const float*)d_in[4];
    const float* comp   = (const float*)d_in[5];
    const float* loopw  = (const float*)d_in[6];
    const float* bias1  = (const float*)d_in[7];
    const float* w2     = (const float*)d_in[8];
    const float* bias2  = (const float*)d_in[9];
    float* out = (float*)d_out;

    char* ws = (char*)d_ws;
    uint32*   part   = (uint32*)(ws + A_PART);
    ushort16* xr     = (ushort16*)(ws + A_XR);   // aliases part; after fill
    float*    y2     = (float*)(ws + A_Y2);      // aliases xr; after agg1
    ushort16* xbf    = (ushort16*)(ws + A_XBF);
    uint32*   degp   = (uint32*)(ws + A_DEGP);
    int*      rowptr = (int*)(ws + A_ROWPTR);
    int*      bsum   = (int*)(ws + A_BSUM);
    int*      bbase  = (int*)(ws + A_BBASE);
    int2*     csr    = (int2*)(ws + A_CSR);
    ushort16* hs     = (ushort16*)(ws + A_HS);
    ushort16* wallbf = (ushort16*)(ws + A_WALL);

    k_wall<<<144, 256, 0, stream>>>(comp, basis, loopw, wallbf);
    k_xbf<<<(N_NODES * 64 / 8 + 255) / 256, 256, 0, stream>>>(x, xbf);
    k_hist2<<<dim3(NB, NQ), 256, 0, stream>>>(ei, part);
    k_merge<<<NBLK2, 256, 0, stream>>>(part, degp, bsum);
    k_scanb<<<1, 256, 0, stream>>>(bsum, bbase);
    k_base<<<NBLK2, 256, 0, stream>>>(part, degp, bbase, rowptr);
    k_fill2<<<dim3(NB, NQ), 256, 0, stream>>>(ei, etype, part, csr);
    k_xr<<<dim3((N_NODES + 63) / 64, 9), 256, 0, stream>>>(xbf, wallbf, xr);
    k_agg1<<<N_NODES / 4, 256, 0, stream>>>(xr, csr, rowptr, degp, bias1, hs);
    k_agg2<<<N_NODES / 4, 256, 0, stream>>>(hs, csr, rowptr, degp, y2);
    k_gemm2<<<(N_NODES + 255) / 256, 256, 0, stream>>>(y2, w2, bias2, out);
}

// Round 13
// 255.780 us; speedup vs baseline: 1.6339x; 1.0186x over previous
//
#include <hip/hip_runtime.h>

#define N_NODES 50000
#define N_EDGES 1000000
#define NB      128         // edge chunks
#define CHUNK   7813        // 128*7813 = 1,000,064 >= E
#define NQ      8           // node ranges per chunk (blockIdx.y)
#define QN      6256        // words per range (16B-aligned); 8*6256 = 50048 >= N
#define NBLK2   196         // ceil(50000/256)

// ---- ws layout (bytes) ----
// Offset 0 is time-shared: part[NB][50000] u32 (25.6 MB, dead after k_fill2)
// -> xr16[50000][9][64] bf16 (57.6 MB, dead after k_agg1)
// -> y2[50000][64] f32 (12.8 MB).
// xbf[50000][64] bf16 (6.4 MB) at 57.6 MB (free hole at all times).
// hs16[50000][64] bf16 (6.4 MB) in the old hs slot.
// csr is u32[1e6] = 4 MB (was int2 8 MB): entry = src*9+etype; src = entry/9.
#define A_PART    0
#define A_XR      0
#define A_Y2      0
#define A_XBF     57600000
#define A_DEGP    115200000  // uint[50000] packed: deg_in<<16 | deg_out
#define A_ROWPTR  115400000  // int[50001]
#define A_BSUM    115600128  // int[196]
#define A_BBASE   115601024  // int[196]
#define A_CSR     115601920  // u32[1e6]: src*9+etype
#define A_HS      123601920  // bf16[50000*64]
#define A_WALL    136401920  // bf16[9*64*64] transposed [r][o][k]
typedef unsigned int uint32;
typedef unsigned short ushort16;
typedef __attribute__((ext_vector_type(8))) short bf16x8;
typedef __attribute__((ext_vector_type(4))) float f32x4;

// bf16 storage helpers: RNE pack, shift unpack. All math stays fp32.
__device__ inline ushort16 f2bf(float f) {
    uint32 u = __float_as_uint(f);
    return (ushort16)((u + 0x7FFFu + ((u >> 16) & 1u)) >> 16);
}
__device__ inline float bf2f(ushort16 h) {
    return __uint_as_float(((uint32)h) << 16);
}

// K0: wallbf[r][o][i] = bf16(sum_b comp[r][b]*basis[b][i][o]); r=8 -> loopw.
// Transposed (o-major) so k_xr's MFMA B-fragments read contiguous k.
__global__ void k_wall(const float* __restrict__ comp, const float* __restrict__ basis,
                       const float* __restrict__ loopw, ushort16* __restrict__ wallbf) {
    int idx = blockIdx.x * 256 + threadIdx.x;
    if (idx >= 9 * 4096) return;
    int r = idx >> 12, io = idx & 4095;
    int i = io >> 6, o = io & 63;
    float acc;
    if (r < 8) {
        acc = 0.f;
        #pragma unroll
        for (int b = 0; b < 30; ++b) acc += comp[r * 30 + b] * basis[b * 4096 + io];
    } else {
        acc = loopw[io];
    }
    wallbf[r * 4096 + o * 64 + i] = f2bf(acc);
}

// K0b: xbf = bf16(x), 8 elements/thread.
__global__ __launch_bounds__(256) void k_xbf(const float* __restrict__ x,
                                             ushort16* __restrict__ xbf) {
    int g = blockIdx.x * 256 + threadIdx.x;
    int base = g * 8;
    if (base >= N_NODES * 64) return;
    float4 v0 = *(const float4*)&x[base];
    float4 v1 = *(const float4*)&x[base + 4];
    uint4 o;
    o.x = (uint32)f2bf(v0.x) | ((uint32)f2bf(v0.y) << 16);
    o.y = (uint32)f2bf(v0.z) | ((uint32)f2bf(v0.w) << 16);
    o.z = (uint32)f2bf(v1.x) | ((uint32)f2bf(v1.y) << 16);
    o.w = (uint32)f2bf(v1.z) | ((uint32)f2bf(v1.w) << 16);
    *(uint4*)&xbf[base] = o;
}

// K1: per-(chunk, node-range) packed histogram via LDS atomics.
// part[b][v] = (in_count<<16) | out_count for chunk b.
// NOTE (v8 lesson): global-atomic build is ~10x slower (2M random atomics =
// 87 us). NOTE (v9 lesson): NQ=4/NB=64 regressed +20 us. Keep NB=128/NQ=8.
__global__ __launch_bounds__(256) void k_hist2(const int* __restrict__ ei,
                                               uint32* __restrict__ part) {
    __shared__ __align__(16) uint32 h[QN];
    int t = threadIdx.x, b = blockIdx.x, q = blockIdx.y;
    int lo = q * QN;
    int nq = N_NODES - lo; if (nq > QN) nq = QN;
    int4* h4 = (int4*)h;
    for (int i = t; i < QN / 4; i += 256) h4[i] = make_int4(0, 0, 0, 0);
    __syncthreads();
    int e0 = b * CHUNK, e1 = e0 + CHUNK;
    if (e1 > N_EDGES) e1 = N_EDGES;
    for (int e = e0 + t; e < e1; e += 256) {
        int s = ei[e], d = ei[N_EDGES + e];
        unsigned rs = (unsigned)(s - lo), rd = (unsigned)(d - lo);
        if (rs < (unsigned)QN) atomicAdd(&h[rs], 1u);
        if (rd < (unsigned)QN) atomicAdd(&h[rd], 0x10000u);
    }
    __syncthreads();
    int4* d4 = (int4*)(part + b * N_NODES + lo);
    const int4* s4 = (const int4*)h;
    for (int i = t; i < nq / 4; i += 256) d4[i] = s4[i];
}

// K2: degp[v] = sum_b part[b][v]; block sums of deg_in for the scan.
__global__ __launch_bounds__(256) void k_merge(const uint32* __restrict__ part,
                                               uint32* __restrict__ degp,
                                               int* __restrict__ bsum) {
    int t = threadIdx.x, v = blockIdx.x * 256 + t;
    uint32 s = 0;
    if (v < N_NODES) {
        #pragma unroll 8
        for (int b = 0; b < NB; ++b) s += part[b * N_NODES + v];
        degp[v] = s;
    }
    int din = (int)(s >> 16);
    int r = din;
    #pragma unroll
    for (int d = 1; d < 64; d <<= 1) r += __shfl_xor(r, d);
    __shared__ int wsum[4];
    int lane = t & 63, wid = t >> 6;
    if (lane == 0) wsum[wid] = r;
    __syncthreads();
    if (t == 0) bsum[blockIdx.x] = wsum[0] + wsum[1] + wsum[2] + wsum[3];
}

// K3: exclusive scan of 196 block sums (single block).
__global__ void k_scanb(const int* __restrict__ bsum, int* __restrict__ bbase) {
    int t = threadIdx.x;
    int v = (t < NBLK2) ? bsum[t] : 0;
    int lane = t & 63, wid = t >> 6;
    int x = v;
    #pragma unroll
    for (int d = 1; d < 64; d <<= 1) {
        int y = __shfl_up(x, d);
        if (lane >= d) x += y;
    }
    __shared__ int wsum[4];
    if (lane == 63) wsum[wid] = x;
    __syncthreads();
    int base = 0;
    for (int w = 0; w < wid; ++w) base += wsum[w];
    if (t < NBLK2) bbase[t] = base + x - v;
}

// K4: rowptr[v]; convert part[b][v] in-place into fill offsets.
__global__ __launch_bounds__(256) void k_base(uint32* __restrict__ part,
                                              const uint32* __restrict__ degp,
                                              const int* __restrict__ bbase,
                                              int* __restrict__ rowptr) {
    int t = threadIdx.x, v = blockIdx.x * 256 + t;
    int din = (v < N_NODES) ? (int)(degp[v] >> 16) : 0;
    int lane = t & 63, wid = t >> 6;
    int x = din;
    #pragma unroll
    for (int d = 1; d < 64; d <<= 1) {
        int y = __shfl_up(x, d);
        if (lane >= d) x += y;
    }
    __shared__ int wsum[4];
    if (lane == 63) wsum[wid] = x;
    __syncthreads();
    int base = bbase[blockIdx.x];
    for (int w = 0; w < wid; ++w) base += wsum[w];
    int start = base + x - din;
    if (v < N_NODES) {
        rowptr[v] = start;
        if (v == N_NODES - 1) rowptr[N_NODES] = start + din;
        uint32 run = (uint32)start;
        for (int b = 0; b < NB; ++b) {
            uint32 p = part[b * N_NODES + v];
            part[b * N_NODES + v] = run;
            run += (p >> 16);
        }
    }
}

// K5: scatter edges into CSR slots; LDS cursors seeded from fillbase.
// v13: csr entry packed to ONE u32 (src*9+etype) — halves the random
// write-allocate line traffic that bound this kernel (46.5 us, all pipes
// <15% busy). agg2 recovers src = entry/9 (magic-mul).
__global__ __launch_bounds__(256) void k_fill2(const int* __restrict__ ei,
                                               const int* __restrict__ etype,
                                               const uint32* __restrict__ fillbase,
                                               uint32* __restrict__ csr) {
    __shared__ __align__(16) uint32 cur[QN];
    int t = threadIdx.x, b = blockIdx.x, q = blockIdx.y;
    int lo = q * QN;
    int nq = N_NODES - lo; if (nq > QN) nq = QN;
    const int4* s4 = (const int4*)(fillbase + b * N_NODES + lo);
    int4* c4 = (int4*)cur;
    for (int i = t; i < nq / 4; i += 256) c4[i] = s4[i];
    __syncthreads();
    int e0 = b * CHUNK, e1 = e0 + CHUNK;
    if (e1 > N_EDGES) e1 = N_EDGES;
    for (int e = e0 + t; e < e1; e += 256) {
        int d = ei[N_EDGES + e];
        unsigned rd = (unsigned)(d - lo);
        if (rd < (unsigned)QN) {
            int s = ei[e], ty = etype[e];
            uint32 pos = atomicAdd(&cur[rd], 1u);
            csr[pos] = (uint32)(s * 9 + ty);
        }
    }
}

// K6 v12: xr via bf16 MFMA (mfma_f32_16x16x32_bf16).
// Block = 64 nodes x 64 outs x 1 relation, 4 waves; wave w owns node rows
// [w*16, w*16+16), iterates 4 col-tiles x 2 k-halves = 8 MFMA.
// LDS: Abf/Wbf with 16B-slot XOR swizzle (slot s of row n at s^(n&7)) +
// Ot repack = 24 KB. Frag layouts (cdna4_isa $10, m89).
__global__ __launch_bounds__(256) void k_xr(const ushort16* __restrict__ xbf,
                                            const ushort16* __restrict__ wallbf,
                                            ushort16* __restrict__ xr) {
    __shared__ __align__(16) ushort16 Abf[64 * 64];
    __shared__ __align__(16) ushort16 Wbf[64 * 64];
    __shared__ __align__(16) ushort16 Ot[64 * 64];
    int t = threadIdx.x;
    int n0 = blockIdx.x * 64;
    int r = blockIdx.y;
    {   // stage A and W: row n = t>>2, slots s0, s0+1 (16 B each)
        int n = t >> 2, s0 = (t & 3) * 2;
        uint4 v0 = make_uint4(0, 0, 0, 0), v1 = v0;
        if (n0 + n < N_NODES) {
            v0 = *(const uint4*)&xbf[(n0 + n) * 64 + s0 * 8];
            v1 = *(const uint4*)&xbf[(n0 + n) * 64 + s0 * 8 + 8];
        }
        *(uint4*)&Abf[n * 64 + ((s0 ^ (n & 7)) * 8)]       = v0;
        *(uint4*)&Abf[n * 64 + (((s0 + 1) ^ (n & 7)) * 8)] = v1;
        uint4 w0 = *(const uint4*)&wallbf[r * 4096 + n * 64 + s0 * 8];
        uint4 w1 = *(const uint4*)&wallbf[r * 4096 + n * 64 + s0 * 8 + 8];
        *(uint4*)&Wbf[n * 64 + ((s0 ^ (n & 7)) * 8)]       = w0;
        *(uint4*)&Wbf[n * 64 + (((s0 + 1) ^ (n & 7)) * 8)] = w1;
    }
    __syncthreads();
    int w = t >> 6, l = t & 63;
    int row = l & 15, kg = l >> 4;          // frag row/col and k-group
    int an = w * 16 + row;
    bf16x8 a0 = *(const bf16x8*)&Abf[an * 64 + (((0 + kg) ^ (an & 7)) * 8)];
    bf16x8 a1 = *(const bf16x8*)&Abf[an * 64 + (((4 + kg) ^ (an & 7)) * 8)];
    #pragma unroll
    for (int ct = 0; ct < 4; ++ct) {
        int bo = ct * 16 + row;
        bf16x8 b0 = *(const bf16x8*)&Wbf[bo * 64 + (((0 + kg) ^ (bo & 7)) * 8)];
        bf16x8 b1 = *(const bf16x8*)&Wbf[bo * 64 + (((4 + kg) ^ (bo & 7)) * 8)];
        f32x4 acc = {0.f, 0.f, 0.f, 0.f};
        acc = __builtin_amdgcn_mfma_f32_16x16x32_bf16(a0, b0, acc, 0, 0, 0);
        acc = __builtin_amdgcn_mfma_f32_16x16x32_bf16(a1, b1, acc, 0, 0, 0);
        #pragma unroll
        for (int j = 0; j < 4; ++j)
            Ot[(w * 16 + kg * 4 + j) * 64 + ct * 16 + row] = f2bf(acc[j]);
    }
    __syncthreads();
    {   // copyout to xr[n][r*64 + o], vectorized
        int n = t >> 2, s = (t & 3) * 2;
        if (n0 + n < N_NODES) {
            *(uint4*)&xr[(n0 + n) * 576 + r * 64 + s * 8] =
                *(const uint4*)&Ot[n * 64 + s * 8];
            *(uint4*)&xr[(n0 + n) * 576 + r * 64 + s * 8 + 8] =
                *(const uint4*)&Ot[n * 64 + s * 8 + 8];
        }
    }
}

// K7: wide gather — 4 CSR rows per VMEM instruction; csr entry u32 is the
// xr row index directly.
__global__ __launch_bounds__(256) void k_agg1(const ushort16* __restrict__ xr,
                                              const uint32* __restrict__ csr,
                                              const int* __restrict__ rowptr,
                                              const uint32* __restrict__ degp,
                                              const float* __restrict__ bias1,
                                              ushort16* __restrict__ hs) {
    int t = threadIdx.x;
    int wid = t >> 6, lane = t & 63;
    int v = blockIdx.x * 4 + wid;
    if (v >= N_NODES) return;
    int sub = lane >> 4, cg = lane & 15;
    float a0 = 0.f, a1 = 0.f, a2 = 0.f, a3 = 0.f;
    int end = rowptr[v + 1];
    for (int j = rowptr[v] + sub; j < end; j += 4) {
        uint32 r0 = csr[j];
        uint2 u = *(const uint2*)&xr[r0 * 64 + cg * 4];
        a0 += __uint_as_float(u.x << 16);
        a1 += __uint_as_float(u.x & 0xffff0000u);
        a2 += __uint_as_float(u.y << 16);
        a3 += __uint_as_float(u.y & 0xffff0000u);
    }
    #pragma unroll
    for (int d = 16; d < 64; d <<= 1) {
        a0 += __shfl_xor(a0, d);
        a1 += __shfl_xor(a1, d);
        a2 += __shfl_xor(a2, d);
        a3 += __shfl_xor(a3, d);
    }
    uint2 slu = *(const uint2*)&xr[(v * 9 + 8) * 64 + cg * 4];
    float4 b = *(const float4*)&bias1[cg * 4];
    a0 += __uint_as_float(slu.x << 16) + b.x;
    a1 += __uint_as_float(slu.x & 0xffff0000u) + b.y;
    a2 += __uint_as_float(slu.y << 16) + b.z;
    a3 += __uint_as_float(slu.y & 0xffff0000u) + b.w;
    float dg = (float)(degp[v] & 0xffffu);
    if (dg < 1.f) dg = 1.f;
    float s = rsqrtf(dg);
    if (sub == 0) {
        uint2 o;
        o.x = (uint32)f2bf(a0 * s) | ((uint32)f2bf(a1 * s) << 16);
        o.y = (uint32)f2bf(a2 * s) | ((uint32)f2bf(a3 * s) << 16);
        *(uint2*)&hs[v * 64 + cg * 4] = o;
    }
}

// K8a: same wide-gather structure over hs16; src recovered as entry/9.
__global__ __launch_bounds__(256) void k_agg2(const ushort16* __restrict__ hs,
                                              const uint32* __restrict__ csr,
                                              const int* __restrict__ rowptr,
                                              const uint32* __restrict__ degp,
                                              float* __restrict__ y2) {
    int t = threadIdx.x;
    int wid = t >> 6, lane = t & 63;
    int v = blockIdx.x * 4 + wid;
    if (v >= N_NODES) return;
    int sub = lane >> 4, cg = lane & 15;
    float a0 = 0.f, a1 = 0.f, a2 = 0.f, a3 = 0.f;
    int end = rowptr[v + 1];
    for (int j = rowptr[v] + sub; j < end; j += 4) {
        uint32 r0 = csr[j] / 9u;   // src (magic-mul divide)
        uint2 u = *(const uint2*)&hs[r0 * 64 + cg * 4];
        a0 += __uint_as_float(u.x << 16);
        a1 += __uint_as_float(u.x & 0xffff0000u);
        a2 += __uint_as_float(u.y << 16);
        a3 += __uint_as_float(u.y & 0xffff0000u);
    }
    #pragma unroll
    for (int d = 16; d < 64; d <<= 1) {
        a0 += __shfl_xor(a0, d);
        a1 += __shfl_xor(a1, d);
        a2 += __shfl_xor(a2, d);
        a3 += __shfl_xor(a3, d);
    }
    float dg = (float)(degp[v] >> 16);
    if (dg < 1.f) dg = 1.f;
    float s = rsqrtf(dg);
    if (sub == 0) {
        *(float4*)&y2[v * 64 + cg * 4] =
            make_float4(a0 * s, a1 * s, a2 * s, a3 * s);
    }
}

// K8b: out = y2 @ w2 + bias2 — batched tiled GEMM (f32, v3-k_xr structure).
__global__ __launch_bounds__(256) void k_gemm2(const float* __restrict__ y2,
                                               const float* __restrict__ w2,
                                               const float* __restrict__ bias2,
                                               float* __restrict__ out) {
    __shared__ __align__(16) float At[32 * 256];   // 32 KB
    __shared__ __align__(16) float Wt[32 * 64];    // 8 KB
    int t = threadIdx.x;
    int n0 = blockIdx.x * 256;
    int og = t & 7, ng = t >> 3;
    float acc[8][8];
    #pragma unroll
    for (int i = 0; i < 8; ++i)
        #pragma unroll
        for (int j = 0; j < 8; ++j) acc[i][j] = 0.f;

    #pragma unroll
    for (int ph = 0; ph < 2; ++ph) {
        if (ph) __syncthreads();
        #pragma unroll
        for (int j = 0; j < 8; ++j) {
            int f4 = t + j * 256;
            int n = f4 >> 3, k4 = f4 & 7;
            float4 v = make_float4(0.f, 0.f, 0.f, 0.f);
            if (n0 + n < N_NODES)
                v = *(const float4*)&y2[(n0 + n) * 64 + ph * 32 + k4 * 4];
            int sl = n >> 2, nl = n & 3, kb = k4 * 4;
            At[(kb + 0) * 256 + (((sl ^ ((kb + 0) & 7)) << 2) | nl)] = v.x;
            At[(kb + 1) * 256 + (((sl ^ ((kb + 1) & 7)) << 2) | nl)] = v.y;
            At[(kb + 2) * 256 + (((sl ^ ((kb + 2) & 7)) << 2) | nl)] = v.z;
            At[(kb + 3) * 256 + (((sl ^ ((kb + 3) & 7)) << 2) | nl)] = v.w;
        }
        #pragma unroll
        for (int j = 0; j < 8; ++j) {
            int f = t + j * 256;
            Wt[f] = w2[ph * 2048 + f];
        }
        __syncthreads();
        #pragma unroll 4
        for (int k = 0; k < 32; ++k) {
            int c = k & 7;
            float4 aA = *(const float4*)&At[k * 256 + (((2 * ng) ^ c) << 2)];
            float4 aB = *(const float4*)&At[k * 256 + (((2 * ng + 1) ^ c) << 2)];
            float4 w0 = *(const float4*)&Wt[k * 64 + og * 8];
            float4 w1 = *(const float4*)&Wt[k * 64 + og * 8 + 4];
            float a_[8] = {aA.x, aA.y, aA.z, aA.w, aB.x, aB.y, aB.z, aB.w};
            float w_[8] = {w0.x, w0.y, w0.z, w0.w, w1.x, w1.y, w1.z, w1.w};
            #pragma unroll
            for (int i = 0; i < 8; ++i)
                #pragma unroll
                for (int j = 0; j < 8; ++j) acc[i][j] += a_[i] * w_[j];
        }
    }
    float4 b0 = *(const float4*)&bias2[og * 8];
    float4 b1 = *(const float4*)&bias2[og * 8 + 4];
    #pragma unroll
    for (int i = 0; i < 8; ++i) {
        int n = n0 + ng * 8 + i;
        if (n < N_NODES) {
            *(float4*)&out[n * 64 + og * 8] =
                make_float4(acc[i][0] + b0.x, acc[i][1] + b0.y,
                            acc[i][2] + b0.z, acc[i][3] + b0.w);
            *(float4*)&out[n * 64 + og * 8 + 4] =
                make_float4(acc[i][4] + b1.x, acc[i][5] + b1.y,
                            acc[i][6] + b1.z, acc[i][7] + b1.w);
        }
    }
}

extern "C" void kernel_launch(void* const* d_in, const int* in_sizes, int n_in,
                              void* d_out, int out_size, void* d_ws, size_t ws_size,
                              hipStream_t stream) {
    const float* x      = (const float*)d_in[0];
    const int*   ei     = (const int*)d_in[1];   // [2E]: src then dst
    const int*   etype  = (const int*)d_in[3];
    const float* basis  = (const float*)d_in[4];
    const float* comp   = (const float*)d_in[5];
    const float* loopw  = (const float*)d_in[6];
    const float* bias1  = (const float*)d_in[7];
    const float* w2     = (const float*)d_in[8];
    const float* bias2  = (const float*)d_in[9];
    float* out = (float*)d_out;

    char* ws = (char*)d_ws;
    uint32*   part   = (uint32*)(ws + A_PART);
    ushort16* xr     = (ushort16*)(ws + A_XR);   // aliases part; after fill
    float*    y2     = (float*)(ws + A_Y2);      // aliases xr; after agg1
    ushort16* xbf    = (ushort16*)(ws + A_XBF);
    uint32*   degp   = (uint32*)(ws + A_DEGP);
    int*      rowptr = (int*)(ws + A_ROWPTR);
    int*      bsum   = (int*)(ws + A_BSUM);
    int*      bbase  = (int*)(ws + A_BBASE);
    uint32*   csr    = (uint32*)(ws + A_CSR);
    ushort16* hs     = (ushort16*)(ws + A_HS);
    ushort16* wallbf = (ushort16*)(ws + A_WALL);

    k_wall<<<144, 256, 0, stream>>>(comp, basis, loopw, wallbf);
    k_xbf<<<(N_NODES * 64 / 8 + 255) / 256, 256, 0, stream>>>(x, xbf);
    k_hist2<<<dim3(NB, NQ), 256, 0, stream>>>(ei, part);
    k_merge<<<NBLK2, 256, 0, stream>>>(part, degp, bsum);
    k_scanb<<<1, 256, 0, stream>>>(bsum, bbase);
    k_base<<<NBLK2, 256, 0, stream>>>(part, degp, bbase, rowptr);
    k_fill2<<<dim3(NB, NQ), 256, 0, stream>>>(ei, etype, part, csr);
    k_xr<<<dim3((N_NODES + 63) / 64, 9), 256, 0, stream>>>(xbf, wallbf, xr);
    k_agg1<<<N_NODES / 4, 256, 0, stream>>>(xr, csr, rowptr, degp, bias1, hs);
    k_agg2<<<N_NODES / 4, 256, 0, stream>>>(hs, csr, rowptr, degp, y2);
    k_gemm2<<<(N_NODES + 255) / 256, 256, 0, stream>>>(y2, w2, bias2, out);
}